// Round 3
// baseline (503.599 us; speedup 1.0000x reference)
//
#include <hip/hip_runtime.h>
#include <cstdint>
#include <cmath>

// ---------------------------------------------------------------------------
// AttentionBlock: x -> MHA(custom scale) -> +res -> LN -> FFN -> +res -> LN
// B=8 S=1024 E=1024 H=16 HD=64 FF=4096, fp32 in/out, fp16 MFMA internally.
// v5b: resubmit of v5 (round-2 container failure diagnosed as infra; schedule
//      re-audited: uniform barriers, FIFO vmcnt accounting, LDS/ws bounds OK).
//      Added sched_barrier(0) after counted vmcnt waits to pin ordering.
//      GEMMs: 256-row deep-pipelined schedule (T3+T4): BM=256, BN 256/128,
//      8 waves, double-buffered chunked LDS, counted vmcnt (never 0 in steady
//      state), raw s_barrier, setprio around MFMA, XCD-chunked block swizzle.
//      attn/LN/cast unchanged from v4 (round-1 passing build).
// ---------------------------------------------------------------------------

typedef _Float16 f16;
typedef _Float16 f16x8 __attribute__((ext_vector_type(8)));
typedef _Float16 f16x4 __attribute__((ext_vector_type(4)));
typedef __bf16   bf16;
typedef __bf16   bf16x8 __attribute__((ext_vector_type(8)));
typedef __bf16   bf16x4 __attribute__((ext_vector_type(4)));
typedef __bf16   bf16x2 __attribute__((ext_vector_type(2)));
typedef float    f32x4  __attribute__((ext_vector_type(4)));
typedef float    f32x16 __attribute__((ext_vector_type(16)));
typedef unsigned int uint2v __attribute__((ext_vector_type(2)));
typedef unsigned int u32x4v __attribute__((ext_vector_type(4)));

#define B_SZ  8
#define S_SZ  1024
#define E_SZ  1024
#define H_SZ  16
#define HD_SZ 64
#define FF_SZ 4096
#define MTOK  (B_SZ * S_SZ)   // 8192 tokens

// async global->LDS, 16B per lane.  LDS dest is wave-uniform base + lane*16.
__device__ __forceinline__ void async_ld16(const void* g, void* l) {
  __builtin_amdgcn_global_load_lds(
      (const __attribute__((address_space(1))) void*)(uintptr_t)g,
      (__attribute__((address_space(3))) void*)(uint32_t)(uintptr_t)l,
      16, 0, 0);
}

template <int N>
__device__ __forceinline__ void wait_vm() {
  if constexpr (N == 0)      asm volatile("s_waitcnt vmcnt(0)" ::: "memory");
  else if constexpr (N == 3) asm volatile("s_waitcnt vmcnt(3)" ::: "memory");
  else if constexpr (N == 4) asm volatile("s_waitcnt vmcnt(4)" ::: "memory");
  else static_assert(N == 0 || N == 3 || N == 4, "unsupported vmcnt");
  __builtin_amdgcn_sched_barrier(0);   // pin: nothing crosses the wait
}

// swap a.lanes[32:63] <-> b.lanes[0:31]
__device__ __forceinline__ void permswap(uint32_t& a, uint32_t& b) {
  uint2v r = __builtin_amdgcn_permlane32_swap(a, b, false, false);
  a = r[0];
  b = r[1];
}

// ---------------------------------------------------------------------------
// fp32 -> fp16 cast (vectorized).
// ---------------------------------------------------------------------------
__global__ void cast_kernel(const float* __restrict__ in, f16* __restrict__ out, int n4) {
  int i = blockIdx.x * blockDim.x + threadIdx.x;
  if (i < n4) {
    float4 f = ((const float4*)in)[i];
    f16x4 o = {(f16)f.x, (f16)f.y, (f16)f.z, (f16)f.w};
    ((f16x4*)out)[i] = o;
  }
}

// ---------------------------------------------------------------------------
// C[M,N] = A[M,K] @ B[N,K]^T  (fp16, K contiguous), fp32 acc.
// Deep-pipelined 256-row tile, 8 waves (512 thr), double-buffered LDS.
// BK=64 as two K=32 slices; each (slice, 128-row-half) is an 8 KB contiguous
// chunk [128][32] f16, octet-swizzled: physical octet = logical ^ ((row>>1)&3)
// -> conflict-free ds_read_b128 fragment reads AND contiguous
// global_load_lds staging.
// Schedule (steady state): while computing slice s of tile t (from buf t&1),
// issue tile t+1's slice-s chunks (NIF = 2+NBCH loads) into buf (t+1)&1.
// Slice-boundary:  s_waitcnt vmcnt(NIF)  -> the previously-issued slice
// needed next is complete (per-wave FIFO), NIF newest stay in flight;
// then raw s_barrier for cross-wave visibility.  vmcnt(0) only at the
// last tile's mid-point drain.
// ---------------------------------------------------------------------------
template <int BN, bool OUT_F16, bool RELU>
__global__ __launch_bounds__(512, 2)
void gemm256(const f16* __restrict__ A, const f16* __restrict__ Bm,
             const float* __restrict__ bias, void* __restrict__ Cp,
             int M, int N, int K, int bf16_from_col) {
  static_assert(BN == 256 || BN == 128, "BN must be 256 or 128");
  constexpr int NBCH  = (BN == 256) ? 2 : 1;   // B row-halves (chunks) per slice
  constexpr int CHUNK = 4096;                  // f16 per 8 KB chunk: [128][32]
  constexpr int NIF   = 2 + NBCH;              // staging issues per K-slice
  constexpr int WN    = (BN == 256) ? 4 : 2;   // waves along N
  constexpr int FM    = (BN == 256) ? 8 : 4;   // M-fragments per wave

  __shared__ f16 lds[(8 + 4 * NBCH) * CHUNK];  // A: 8 chunks, B: 4*NBCH chunks
  f16* Ab = lds;                               // [buf][slice][half]*CHUNK
  f16* Bb = lds + 8 * CHUNK;

  const int tid  = threadIdx.x;
  const int wave = tid >> 6;
  const int lane = tid & 63;
  const int quad = lane >> 4;
  const int l16  = lane & 15;

  const int wm  = wave / WN;
  const int wn  = wave % WN;
  const int ah  = (BN == 256) ? wm : (wm >> 1);        // wave's A row-half
  const int amB = (BN == 256) ? 0 : (wm & 1) * 64;     // row base within half
  const int bh  = (BN == 256) ? (wn >> 1) : 0;         // wave's B row-half
  const int bnB = (BN == 256) ? (wn & 1) * 64 : wn * 64;

  // block decode with XCD-chunked swizzle (consecutive dispatch ids
  // round-robin XCDs; give each XCD a contiguous logical chunk).
  int logical = blockIdx.x;
  {
    const int nwg = gridDim.x;
    if ((nwg & 7) == 0) logical = (logical & 7) * (nwg >> 3) + (logical >> 3);
  }
  const int gx = N / BN;
  const int bn = logical % gx;
  const int bm = logical / gx;

  f32x4 acc[FM][4];
#pragma unroll
  for (int mi = 0; mi < FM; mi++)
#pragma unroll
    for (int ni = 0; ni < 4; ni++) acc[mi][ni] = (f32x4){0.f, 0.f, 0.f, 0.f};

  // staging thread params: thread covers chunk row rr_s, physical octet tid&3,
  // holding logical octet lo_s = (tid&3) ^ ((rr_s>>1)&3).
  const int rr_s = tid >> 2;
  const int lo_s = (tid & 3) ^ ((rr_s >> 1) & 3);
  const int wofs = wave * 512;   // wave's 1 KB slot inside a chunk (f16 units)
  const f16* gAb = A  + ((size_t)bm * 256 + rr_s) * (size_t)K + lo_s * 8;
  const f16* gBb = Bm + ((size_t)bn * BN  + rr_s) * (size_t)K + lo_s * 8;

  auto stA = [&](int bb, int s, int h, int kt) {
    async_ld16(gAb + (size_t)h * 128 * K + kt * 64 + s * 32,
               Ab + ((((bb << 1) + s) << 1) + h) * CHUNK + wofs);
  };
  auto stB = [&](int bb, int s, int h, int kt) {
    async_ld16(gBb + (size_t)h * 128 * K + kt * 64 + s * 32,
               Bb + (((bb << 1) + s) * NBCH + h) * CHUNK + wofs);
  };
  auto rdFrag = [&](const f16* ch, int rr) -> f16x8 {
    return *(const f16x8*)&ch[rr * 32 + ((quad ^ ((rr >> 1) & 3)) << 3)];
  };

  const int NT = K >> 6;

  // ---- prologue: stage tile 0 (slice 0 then slice 1) into buf 0 ----
#pragma unroll
  for (int s = 0; s < 2; s++) {
    stA(0, s, 0, 0);
    stA(0, s, 1, 0);
    stB(0, s, 0, 0);
    if constexpr (NBCH == 2) stB(0, s, 1, 0);
  }
  wait_vm<NIF>();                       // tile0 slice0 complete, slice1 in flight
  __builtin_amdgcn_s_barrier();

  for (int t = 0; t < NT; t++) {
    const int cur = t & 1, oth = cur ^ 1;
    const bool last = (t == NT - 1);
#pragma unroll
    for (int s = 0; s < 2; s++) {
      if (!last) { stA(oth, s, 0, t + 1); stA(oth, s, 1, t + 1); }
      const f16* Ach = Ab + ((((cur << 1) + s) << 1) + ah) * CHUNK;
      const f16* Bch = Bb + (((cur << 1) + s) * NBCH + bh) * CHUNK;
      f16x8 bfr[4];
#pragma unroll
      for (int ni = 0; ni < 4; ni++) bfr[ni] = rdFrag(Bch, bnB + ni * 16 + l16);

      if constexpr (BN == 256) {
        f16x8 af[4];
#pragma unroll
        for (int i = 0; i < 4; i++) af[i] = rdFrag(Ach, amB + i * 16 + l16);
        __builtin_amdgcn_s_setprio(1);
#pragma unroll
        for (int i = 0; i < 4; i++)
#pragma unroll
          for (int ni = 0; ni < 4; ni++)
            acc[i][ni] = __builtin_amdgcn_mfma_f32_16x16x32_f16(af[i], bfr[ni], acc[i][ni], 0, 0, 0);
        __builtin_amdgcn_s_setprio(0);
        __builtin_amdgcn_s_barrier();   // lockstep between the two mi-phases
        if (!last) { stB(oth, s, 0, t + 1); stB(oth, s, 1, t + 1); }
#pragma unroll
        for (int i = 0; i < 4; i++) af[i] = rdFrag(Ach, amB + (4 + i) * 16 + l16);
        __builtin_amdgcn_s_setprio(1);
#pragma unroll
        for (int i = 0; i < 4; i++)
#pragma unroll
          for (int ni = 0; ni < 4; ni++)
            acc[4 + i][ni] = __builtin_amdgcn_mfma_f32_16x16x32_f16(af[i], bfr[ni], acc[4 + i][ni], 0, 0, 0);
        __builtin_amdgcn_s_setprio(0);
      } else {
        if (!last) stB(oth, s, 0, t + 1);
        f16x8 af[4];
#pragma unroll
        for (int i = 0; i < 4; i++) af[i] = rdFrag(Ach, amB + i * 16 + l16);
        __builtin_amdgcn_s_setprio(1);
#pragma unroll
        for (int i = 0; i < 4; i++)
#pragma unroll
          for (int ni = 0; ni < 4; ni++)
            acc[i][ni] = __builtin_amdgcn_mfma_f32_16x16x32_f16(af[i], bfr[ni], acc[i][ni], 0, 0, 0);
        __builtin_amdgcn_s_setprio(0);
      }

      // slice boundary: make the next-needed slice visible.
      if (!last) {
        wait_vm<NIF>();                 // oldest NIF (next slice's chunks) done
        __builtin_amdgcn_s_barrier();
      } else if (s == 0) {
        wait_vm<0>();                   // final drain: last tile's slice 1
        __builtin_amdgcn_s_barrier();
      }
    }
  }

  // ---- epilogue ----
  const int rowW = bm * 256 + ((BN == 256) ? wm * 128 : wm * 64);
  const int colW = bn * BN + wn * 64;
  const bool store_bf16 = OUT_F16 && (bn * BN >= bf16_from_col);
#pragma unroll
  for (int ni = 0; ni < 4; ni++) {
    const int col = colW + ni * 16 + l16;
    const float bv = (bias != nullptr) ? bias[col] : 0.f;
#pragma unroll
    for (int mi = 0; mi < FM; mi++) {
#pragma unroll
      for (int r = 0; r < 4; r++) {
        const int row = rowW + mi * 16 + quad * 4 + r;
        float v = acc[mi][ni][r] + bv;
        if (RELU) v = fmaxf(v, 0.f);
        if (OUT_F16) {
          if (store_bf16)
            ((bf16*)Cp)[(size_t)row * N + col] = (bf16)v;
          else
            ((f16*)Cp)[(size_t)row * N + col] = (f16)v;
        } else {
          ((float*)Cp)[(size_t)row * N + col] = v;
        }
      }
    }
  }
  (void)M;
}

// ---------------------------------------------------------------------------
// Fused flash attention v4 (32x32x16 MFMA) -- unchanged (round-1 passing).
// ---------------------------------------------------------------------------
__global__ __launch_bounds__(256, 4)
void attn_kernel(const f16* __restrict__ qkv, f16* __restrict__ ctx,
                 float scale2, float c2) {
  __shared__ __align__(16) char pool[33280];
  f16*  Ks = (f16*)pool;              // [key 0..127] x 64 f16, XOR-octet swizzle; Q preload overlays
  bf16* Vt = (bf16*)(pool + 16384);   // [d 0..63] stride 132 bf16

  const int tid  = threadIdx.x;
  const int wave = tid >> 6;
  const int lane = tid & 63;
  const int l31  = lane & 31;
  const int hi   = lane >> 5;

  const int flat = blockIdx.x;
  const int bh   = flat & 127;
  const int qt   = flat >> 7;
  const int b    = bh >> 4;
  const int h    = bh & 15;

  const int rs = 3 * E_SZ;
  const size_t tokbase = (size_t)b * S_SZ;

  const int su  = lane >> 3;
  const int soc = (lane & 7) ^ su;

  {
    const f16* gq = qkv + (tokbase + qt * 128 + wave * 8 + su) * (size_t)rs + h * HD_SZ + soc * 8;
#pragma unroll
    for (int i = 0; i < 4; i++)
      async_ld16(gq + (size_t)i * 32 * rs, pool + (i * 32 + wave * 8) * 128);
  }
  __syncthreads();

  f16x8 aq[4];
  {
    const int qrow = wave * 32 + l31;
#pragma unroll
    for (int ks = 0; ks < 4; ks++)
      aq[ks] = *(const f16x8*)&Ks[qrow * 64 + (((ks * 2 + hi) ^ (qrow & 7)) << 3)];
  }

  float Lp = 0.f;
  f32x16 oacc[2];
#pragma unroll
  for (int nb = 0; nb < 2; nb++)
#pragma unroll
    for (int i = 0; i < 16; i++) oacc[nb][i] = 0.f;

  const int vc  = (tid & 7) * 8;
  const int vk0 = (tid >> 3) * 4;

  for (int t = 0; t < S_SZ / 128; t++) {
    __syncthreads();
    {
      const f16* gk = qkv + (tokbase + t * 128 + wave * 8 + su) * (size_t)rs + E_SZ + h * HD_SZ + soc * 8;
#pragma unroll
      for (int i = 0; i < 4; i++)
        async_ld16(gk + (size_t)i * 32 * rs, pool + (i * 32 + wave * 8) * 128);
    }
    {
      const bf16* gv = (const bf16*)qkv + (tokbase + t * 128 + vk0) * (size_t)rs + 2 * E_SZ + h * HD_SZ + vc;
      bf16x8 v0 = *(const bf16x8*)(gv);
      bf16x8 v1 = *(const bf16x8*)(gv + rs);
      bf16x8 v2 = *(const bf16x8*)(gv + 2 * rs);
      bf16x8 v3 = *(const bf16x8*)(gv + 3 * rs);
#pragma unroll
      for (int e = 0; e < 8; e++) {
        bf16x4 pk = {v0[e], v1[e], v2[e], v3[e]};
        *(bf16x4*)&Vt[(vc + e) * 132 + vk0] = pk;
      }
    }
    __syncthreads();

#pragma unroll
    for (int nt = 0; nt < 4; nt++) {
      f32x16 sacc;
#pragma unroll
      for (int i = 0; i < 16; i++) sacc[i] = 0.f;

      const int krow = nt * 32 + l31;
      __builtin_amdgcn_s_setprio(1);
#pragma unroll
      for (int ks = 0; ks < 4; ks++) {
        f16x8 kf = *(const f16x8*)&Ks[krow * 64 + (((ks * 2 + hi) ^ (krow & 7)) << 3)];
        sacc = __builtin_amdgcn_mfma_f32_32x32x16_f16(kf, aq[ks], sacc, 0, 0, 0);
      }
      __builtin_amdgcn_s_setprio(0);

      uint32_t w[8];
#pragma unroll
      for (int j = 0; j < 8; j++) {
        float p0 = exp2f(fmaf(sacc[2 * j],     scale2, -c2));
        float p1 = exp2f(fmaf(sacc[2 * j + 1], scale2, -c2));
        Lp += p0 + p1;
        bf16x2 pk2 = {(bf16)p0, (bf16)p1};
        w[j] = __builtin_bit_cast(uint32_t, pk2);
      }
      permswap(w[0], w[2]);
      permswap(w[1], w[3]);
      permswap(w[4], w[6]);
      permswap(w[5], w[7]);
      u32x4v pe = {w[0], w[1], w[2], w[3]};
      u32x4v po = {w[4], w[5], w[6], w[7]};
      bf16x8 pa[2] = {__builtin_bit_cast(bf16x8, pe), __builtin_bit_cast(bf16x8, po)};

      __builtin_amdgcn_s_setprio(1);
#pragma unroll
      for (int nb = 0; nb < 2; nb++) {
        const int d = nb * 32 + l31;
#pragma unroll
        for (int kst = 0; kst < 2; kst++) {
          const int key = (nt * 2 + kst) * 16 + hi * 8;
          bf16x4 blo = *(const bf16x4*)&Vt[d * 132 + key];
          bf16x4 bhi = *(const bf16x4*)&Vt[d * 132 + key + 4];
          bf16x8 bv = __builtin_shufflevector(blo, bhi, 0, 1, 2, 3, 4, 5, 6, 7);
          oacc[nb] = __builtin_amdgcn_mfma_f32_32x32x16_bf16(pa[kst], bv, oacc[nb], 0, 0, 0);
        }
      }
      __builtin_amdgcn_s_setprio(0);
    }
  }

  float Lfull = Lp + __shfl_xor(Lp, 32, 64);
  const float inv = 1.f / Lfull;
#pragma unroll
  for (int r = 0; r < 16; r++) {
    const int qrow = (r & 3) + 8 * (r >> 2) + 4 * hi;
    const float invr = __shfl(inv, qrow, 32);
    const size_t row = tokbase + (size_t)qt * 128 + wave * 32 + qrow;
#pragma unroll
    for (int nb = 0; nb < 2; nb++)
      ctx[row * (size_t)E_SZ + h * HD_SZ + nb * 32 + l31] = (f16)(oacc[nb][r] * invr);
  }
}

// ---------------------------------------------------------------------------
// LayerNorm(a + res) * g + b  over rows of 1024, fp32 (+optional f16 copy).
// ---------------------------------------------------------------------------
__global__ void ln_kernel(const float* __restrict__ a, const float* __restrict__ res,
                          const float* __restrict__ g, const float* __restrict__ bta,
                          float* __restrict__ out32, f16* __restrict__ out16) {
  const int row  = blockIdx.x;
  const int tid  = threadIdx.x;
  const int wave = tid >> 6;
  const int lane = tid & 63;
  const size_t base = (size_t)row * 1024;
  const int c = tid * 4;

  float4 va = *(const float4*)&a[base + c];
  float4 vr = *(const float4*)&res[base + c];
  float v0 = va.x + vr.x, v1 = va.y + vr.y, v2 = va.z + vr.z, v3 = va.w + vr.w;

  __shared__ float r1[4], r2[4];
  float s = v0 + v1 + v2 + v3;
#pragma unroll
  for (int off = 32; off; off >>= 1) s += __shfl_xor(s, off, 64);
  if (lane == 0) r1[wave] = s;
  __syncthreads();
  const float mu = (r1[0] + r1[1] + r1[2] + r1[3]) * (1.f / 1024.f);

  float d0 = v0 - mu, d1 = v1 - mu, d2 = v2 - mu, d3 = v3 - mu;
  float ss = d0 * d0 + d1 * d1 + d2 * d2 + d3 * d3;
#pragma unroll
  for (int off = 32; off; off >>= 1) ss += __shfl_xor(ss, off, 64);
  if (lane == 0) r2[wave] = ss;
  __syncthreads();
  const float var = (r2[0] + r2[1] + r2[2] + r2[3]) * (1.f / 1024.f);
  const float rsq = rsqrtf(var + 1e-5f);

  float4 gg = *(const float4*)&g[c];
  float4 bb = *(const float4*)&bta[c];
  float o0 = d0 * rsq * gg.x + bb.x;
  float o1 = d1 * rsq * gg.y + bb.y;
  float o2 = d2 * rsq * gg.z + bb.z;
  float o3 = d3 * rsq * gg.w + bb.w;
  float4 o = {o0, o1, o2, o3};
  *(float4*)&out32[base + c] = o;
  if (out16 != nullptr) {
    f16x4 ob = {(f16)o0, (f16)o1, (f16)o2, (f16)o3};
    *(f16x4*)&out16[base + c] = ob;
  }
}

// ---------------------------------------------------------------------------
// Launch
// ---------------------------------------------------------------------------
extern "C" void kernel_launch(void* const* d_in, const int* in_sizes, int n_in,
                              void* d_out, int out_size, void* d_ws, size_t ws_size,
                              hipStream_t stream) {
  const float* x    = (const float*)d_in[0];
  const float* wqkv = (const float*)d_in[1];
  const float* wo   = (const float*)d_in[2];
  const float* ln1g = (const float*)d_in[3];
  const float* ln1b = (const float*)d_in[4];
  const float* ln2g = (const float*)d_in[5];
  const float* ln2b = (const float*)d_in[6];
  const float* w1   = (const float*)d_in[7];
  const float* b1   = (const float*)d_in[8];
  const float* w2   = (const float*)d_in[9];
  const float* b2   = (const float*)d_in[10];
  float* out = (float*)d_out;

  char* ws = (char*)d_ws;
  f16* w_inb  = (f16*)(ws + 0);
  f16* w_outb = (f16*)(ws + 6291456);
  f16* w1b    = (f16*)(ws + 8388608);
  f16* w2b    = (f16*)(ws + 16777216);
  f16* xb     = (f16*)(ws + 25165824);
  f16* qkv    = (f16*)(ws + 41943040);   // q,k fp16 | v-third bf16
  f16* ctx    = (f16*)(ws + 92274688);
  f16* ff1    = (f16*)(ws + 41943040);
  float* tmp  = (float*)(ws + 109051904);
  float* hbuf = (float*)(ws + 142606336);
  f16* hb     = xb;

  const int NOBF = 1 << 30;

  cast_kernel<<<3072, 256, 0, stream>>>(wqkv, w_inb, 3 * E_SZ * E_SZ / 4);
  cast_kernel<<<1024, 256, 0, stream>>>(wo, w_outb, E_SZ * E_SZ / 4);
  cast_kernel<<<4096, 256, 0, stream>>>(w1, w1b, FF_SZ * E_SZ / 4);
  cast_kernel<<<4096, 256, 0, stream>>>(w2, w2b, E_SZ * FF_SZ / 4);
  cast_kernel<<<8192, 256, 0, stream>>>(x, xb, MTOK * E_SZ / 4);

  // qkv = x @ in_proj_w^T; V-third (cols >= 2048) stored bf16
  gemm256<256, true, false><<<(3 * E_SZ / 256) * (MTOK / 256), 512, 0, stream>>>(
      xb, w_inb, nullptr, qkv, MTOK, 3 * E_SZ, E_SZ, 2048);

  // p = 2^(2.5*dot - 60): 0.25*ln(1024)*log2(e) == 2.5 exactly
  attn_kernel<<<1024, 256, 0, stream>>>(qkv, ctx, 2.5f, 60.0f);

  gemm256<128, false, false><<<(E_SZ / 128) * (MTOK / 256), 512, 0, stream>>>(
      ctx, w_outb, nullptr, tmp, MTOK, E_SZ, E_SZ, NOBF);

  ln_kernel<<<MTOK, 256, 0, stream>>>(tmp, x, ln1g, ln1b, hbuf, hb);

  gemm256<256, true, true><<<(FF_SZ / 256) * (MTOK / 256), 512, 0, stream>>>(
      hb, w1b, b1, ff1, MTOK, FF_SZ, E_SZ, NOBF);

  gemm256<128, false, false><<<(E_SZ / 128) * (MTOK / 256), 512, 0, stream>>>(
      ff1, w2b, b2, tmp, MTOK, E_SZ, FF_SZ, NOBF);

  ln_kernel<<<MTOK, 256, 0, stream>>>(tmp, hbuf, ln2g, ln2b, out, nullptr);

  (void)in_sizes; (void)n_in; (void)out_size; (void)ws_size;
}

// Round 4
// 494.749 us; speedup vs baseline: 1.0179x; 1.0179x over previous
//
#include <hip/hip_runtime.h>
#include <cstdint>
#include <cmath>

// ---------------------------------------------------------------------------
// AttentionBlock: x -> MHA(custom scale) -> +res -> LN -> FFN -> +res -> LN
// B=8 S=1024 E=1024 H=16 HD=64 FF=4096, fp32 in/out, fp16 MFMA internally.
// v6: gemm256 phases re-ordered to the proven 8-phase template: ds_reads and
//     stage-issues BEFORE the pre-MFMA barrier, lgkmcnt(0)+sched_barrier(0)
//     after it, setprio around the 16-MFMA cluster, slice boundary =
//     vmcnt(NIF)+s_barrier (counted, never 0 in steady state).
//     attn/LN/cast byte-identical to the round-3 passing build.
// ---------------------------------------------------------------------------

typedef _Float16 f16;
typedef _Float16 f16x8 __attribute__((ext_vector_type(8)));
typedef _Float16 f16x4 __attribute__((ext_vector_type(4)));
typedef __bf16   bf16;
typedef __bf16   bf16x8 __attribute__((ext_vector_type(8)));
typedef __bf16   bf16x4 __attribute__((ext_vector_type(4)));
typedef __bf16   bf16x2 __attribute__((ext_vector_type(2)));
typedef float    f32x4  __attribute__((ext_vector_type(4)));
typedef float    f32x16 __attribute__((ext_vector_type(16)));
typedef unsigned int uint2v __attribute__((ext_vector_type(2)));
typedef unsigned int u32x4v __attribute__((ext_vector_type(4)));

#define B_SZ  8
#define S_SZ  1024
#define E_SZ  1024
#define H_SZ  16
#define HD_SZ 64
#define FF_SZ 4096
#define MTOK  (B_SZ * S_SZ)   // 8192 tokens

// async global->LDS, 16B per lane.  LDS dest is wave-uniform base + lane*16.
__device__ __forceinline__ void async_ld16(const void* g, void* l) {
  __builtin_amdgcn_global_load_lds(
      (const __attribute__((address_space(1))) void*)(uintptr_t)g,
      (__attribute__((address_space(3))) void*)(uint32_t)(uintptr_t)l,
      16, 0, 0);
}

template <int N>
__device__ __forceinline__ void wait_vm() {
  if constexpr (N == 0)      asm volatile("s_waitcnt vmcnt(0)" ::: "memory");
  else if constexpr (N == 3) asm volatile("s_waitcnt vmcnt(3)" ::: "memory");
  else if constexpr (N == 4) asm volatile("s_waitcnt vmcnt(4)" ::: "memory");
  else static_assert(N == 0 || N == 3 || N == 4, "unsupported vmcnt");
  __builtin_amdgcn_sched_barrier(0);   // pin: nothing crosses the wait
}

__device__ __forceinline__ void wait_lgkm0_fenced() {
  asm volatile("s_waitcnt lgkmcnt(0)" ::: "memory");
  __builtin_amdgcn_sched_barrier(0);   // rule #18: keep MFMA below the wait
}

// swap a.lanes[32:63] <-> b.lanes[0:31]
__device__ __forceinline__ void permswap(uint32_t& a, uint32_t& b) {
  uint2v r = __builtin_amdgcn_permlane32_swap(a, b, false, false);
  a = r[0];
  b = r[1];
}

// ---------------------------------------------------------------------------
// fp32 -> fp16 cast (vectorized).
// ---------------------------------------------------------------------------
__global__ void cast_kernel(const float* __restrict__ in, f16* __restrict__ out, int n4) {
  int i = blockIdx.x * blockDim.x + threadIdx.x;
  if (i < n4) {
    float4 f = ((const float4*)in)[i];
    f16x4 o = {(f16)f.x, (f16)f.y, (f16)f.z, (f16)f.w};
    ((f16x4*)out)[i] = o;
  }
}

// ---------------------------------------------------------------------------
// C[M,N] = A[M,K] @ B[N,K]^T  (fp16, K contiguous), fp32 acc.
// Deep-pipelined 256-row tile, 8 waves (512 thr), double-buffered LDS.
// BK=64 as two K=32 slices; each (slice, 128-row-half) is an 8 KB contiguous
// chunk [128][32] f16, octet-swizzled: physical octet = logical ^ ((row>>1)&3).
// Per phase (template-faithful): { ds_read current-slice frags; issue next
// tile's stage loads } -> sched_barrier -> s_barrier -> lgkmcnt(0)+sched ->
// setprio(1) 16 MFMA setprio(0).  BN=256: two phases per slice (m0-3, m4-7,
// B-frags live across both).  Slice boundary: vmcnt(NIF)+s_barrier makes the
// next slice visible while NIF newest loads stay in flight; vmcnt(0) only at
// the last tile's mid-point drain.
// ---------------------------------------------------------------------------
template <int BN, bool OUT_F16, bool RELU>
__global__ __launch_bounds__(512, 2)
void gemm256(const f16* __restrict__ A, const f16* __restrict__ Bm,
             const float* __restrict__ bias, void* __restrict__ Cp,
             int M, int N, int K, int bf16_from_col) {
  static_assert(BN == 256 || BN == 128, "BN must be 256 or 128");
  constexpr int NBCH  = (BN == 256) ? 2 : 1;   // B row-halves (chunks) per slice
  constexpr int CHUNK = 4096;                  // f16 per 8 KB chunk: [128][32]
  constexpr int NIF   = 2 + NBCH;              // staging issues per K-slice
  constexpr int WN    = (BN == 256) ? 4 : 2;   // waves along N
  constexpr int FM    = (BN == 256) ? 8 : 4;   // M-fragments per wave

  __shared__ f16 lds[(8 + 4 * NBCH) * CHUNK];  // A: 8 chunks, B: 4*NBCH chunks
  f16* Ab = lds;                               // [buf][slice][half]*CHUNK
  f16* Bb = lds + 8 * CHUNK;

  const int tid  = threadIdx.x;
  const int wave = tid >> 6;
  const int lane = tid & 63;
  const int quad = lane >> 4;
  const int l16  = lane & 15;

  const int wm  = wave / WN;
  const int wn  = wave % WN;
  const int ah  = (BN == 256) ? wm : (wm >> 1);        // wave's A row-half
  const int amB = (BN == 256) ? 0 : (wm & 1) * 64;     // row base within half
  const int bh  = (BN == 256) ? (wn >> 1) : 0;         // wave's B row-half
  const int bnB = (BN == 256) ? (wn & 1) * 64 : wn * 64;

  // block decode with XCD-chunked swizzle.
  int logical = blockIdx.x;
  {
    const int nwg = gridDim.x;
    if ((nwg & 7) == 0) logical = (logical & 7) * (nwg >> 3) + (logical >> 3);
  }
  const int gx = N / BN;
  const int bn = logical % gx;
  const int bm = logical / gx;

  f32x4 acc[FM][4];
#pragma unroll
  for (int mi = 0; mi < FM; mi++)
#pragma unroll
    for (int ni = 0; ni < 4; ni++) acc[mi][ni] = (f32x4){0.f, 0.f, 0.f, 0.f};

  // staging thread params: thread covers chunk row rr_s, physical octet tid&3,
  // holding logical octet lo_s = (tid&3) ^ ((rr_s>>1)&3).
  const int rr_s = tid >> 2;
  const int lo_s = (tid & 3) ^ ((rr_s >> 1) & 3);
  const int wofs = wave * 512;   // wave's 1 KB slot inside a chunk (f16 units)
  const f16* gAb = A  + ((size_t)bm * 256 + rr_s) * (size_t)K + lo_s * 8;
  const f16* gBb = Bm + ((size_t)bn * BN  + rr_s) * (size_t)K + lo_s * 8;

  auto stA = [&](int bb, int s, int h, int kt) {
    async_ld16(gAb + (size_t)h * 128 * K + kt * 64 + s * 32,
               Ab + ((((bb << 1) + s) << 1) + h) * CHUNK + wofs);
  };
  auto stB = [&](int bb, int s, int h, int kt) {
    async_ld16(gBb + (size_t)h * 128 * K + kt * 64 + s * 32,
               Bb + (((bb << 1) + s) * NBCH + h) * CHUNK + wofs);
  };
  auto rdFrag = [&](const f16* ch, int rr) -> f16x8 {
    return *(const f16x8*)&ch[rr * 32 + ((quad ^ ((rr >> 1) & 3)) << 3)];
  };

  const int NT = K >> 6;

  // ---- prologue: stage tile 0 (slice 0 then slice 1) into buf 0 ----
#pragma unroll
  for (int s = 0; s < 2; s++) {
    stA(0, s, 0, 0);
    stA(0, s, 1, 0);
    stB(0, s, 0, 0);
    if constexpr (NBCH == 2) stB(0, s, 1, 0);
  }
  wait_vm<NIF>();                       // tile0 slice0 complete, slice1 in flight
  __builtin_amdgcn_s_barrier();

  for (int t = 0; t < NT; t++) {
    const int cur = t & 1, oth = cur ^ 1;
    const bool last = (t == NT - 1);
#pragma unroll
    for (int s = 0; s < 2; s++) {
      const f16* Ach = Ab + ((((cur << 1) + s) << 1) + ah) * CHUNK;
      const f16* Bch = Bb + (((cur << 1) + s) * NBCH + bh) * CHUNK;

      // ---- phase A: reads + stage issues BEFORE the barrier ----
      f16x8 bfr[4], af[4];
#pragma unroll
      for (int ni = 0; ni < 4; ni++) bfr[ni] = rdFrag(Bch, bnB + ni * 16 + l16);
#pragma unroll
      for (int i = 0; i < 4; i++) af[i] = rdFrag(Ach, amB + i * 16 + l16);
      if (!last) {
        stA(oth, s, 0, t + 1);
        stA(oth, s, 1, t + 1);
        if constexpr (NBCH == 1) stB(oth, s, 0, t + 1);
      }
      __builtin_amdgcn_sched_barrier(0);
      __builtin_amdgcn_s_barrier();
      wait_lgkm0_fenced();
      __builtin_amdgcn_s_setprio(1);
#pragma unroll
      for (int i = 0; i < 4; i++)
#pragma unroll
        for (int ni = 0; ni < 4; ni++)
          acc[i][ni] = __builtin_amdgcn_mfma_f32_16x16x32_f16(af[i], bfr[ni], acc[i][ni], 0, 0, 0);
      __builtin_amdgcn_s_setprio(0);

      if constexpr (BN == 256) {
        // ---- phase B: second m-half, B-frags still live ----
        __builtin_amdgcn_s_barrier();
#pragma unroll
        for (int i = 0; i < 4; i++) af[i] = rdFrag(Ach, amB + (4 + i) * 16 + l16);
        if (!last) {
          stB(oth, s, 0, t + 1);
          stB(oth, s, 1, t + 1);
        }
        __builtin_amdgcn_sched_barrier(0);
        __builtin_amdgcn_s_barrier();
        wait_lgkm0_fenced();
        __builtin_amdgcn_s_setprio(1);
#pragma unroll
        for (int i = 0; i < 4; i++)
#pragma unroll
          for (int ni = 0; ni < 4; ni++)
            acc[4 + i][ni] = __builtin_amdgcn_mfma_f32_16x16x32_f16(af[i], bfr[ni], acc[4 + i][ni], 0, 0, 0);
        __builtin_amdgcn_s_setprio(0);
      }

      // ---- slice boundary: make the next-needed slice visible ----
      if (!last) {
        wait_vm<NIF>();                 // oldest NIF (next slice's chunks) done
        __builtin_amdgcn_s_barrier();
      } else if (s == 0) {
        wait_vm<0>();                   // final drain: last tile's slice 1
        __builtin_amdgcn_s_barrier();
      }
    }
  }

  // ---- epilogue ----
  const int rowW = bm * 256 + ((BN == 256) ? wm * 128 : wm * 64);
  const int colW = bn * BN + wn * 64;
  const bool store_bf16 = OUT_F16 && (bn * BN >= bf16_from_col);
#pragma unroll
  for (int ni = 0; ni < 4; ni++) {
    const int col = colW + ni * 16 + l16;
    const float bv = (bias != nullptr) ? bias[col] : 0.f;
#pragma unroll
    for (int mi = 0; mi < FM; mi++) {
#pragma unroll
      for (int r = 0; r < 4; r++) {
        const int row = rowW + mi * 16 + quad * 4 + r;
        float v = acc[mi][ni][r] + bv;
        if (RELU) v = fmaxf(v, 0.f);
        if (OUT_F16) {
          if (store_bf16)
            ((bf16*)Cp)[(size_t)row * N + col] = (bf16)v;
          else
            ((f16*)Cp)[(size_t)row * N + col] = (f16)v;
        } else {
          ((float*)Cp)[(size_t)row * N + col] = v;
        }
      }
    }
  }
  (void)M;
}

// ---------------------------------------------------------------------------
// Fused flash attention v4 (32x32x16 MFMA) -- unchanged (round-1 passing).
// ---------------------------------------------------------------------------
__global__ __launch_bounds__(256, 4)
void attn_kernel(const f16* __restrict__ qkv, f16* __restrict__ ctx,
                 float scale2, float c2) {
  __shared__ __align__(16) char pool[33280];
  f16*  Ks = (f16*)pool;              // [key 0..127] x 64 f16, XOR-octet swizzle; Q preload overlays
  bf16* Vt = (bf16*)(pool + 16384);   // [d 0..63] stride 132 bf16

  const int tid  = threadIdx.x;
  const int wave = tid >> 6;
  const int lane = tid & 63;
  const int l31  = lane & 31;
  const int hi   = lane >> 5;

  const int flat = blockIdx.x;
  const int bh   = flat & 127;
  const int qt   = flat >> 7;
  const int b    = bh >> 4;
  const int h    = bh & 15;

  const int rs = 3 * E_SZ;
  const size_t tokbase = (size_t)b * S_SZ;

  const int su  = lane >> 3;
  const int soc = (lane & 7) ^ su;

  {
    const f16* gq = qkv + (tokbase + qt * 128 + wave * 8 + su) * (size_t)rs + h * HD_SZ + soc * 8;
#pragma unroll
    for (int i = 0; i < 4; i++)
      async_ld16(gq + (size_t)i * 32 * rs, pool + (i * 32 + wave * 8) * 128);
  }
  __syncthreads();

  f16x8 aq[4];
  {
    const int qrow = wave * 32 + l31;
#pragma unroll
    for (int ks = 0; ks < 4; ks++)
      aq[ks] = *(const f16x8*)&Ks[qrow * 64 + (((ks * 2 + hi) ^ (qrow & 7)) << 3)];
  }

  float Lp = 0.f;
  f32x16 oacc[2];
#pragma unroll
  for (int nb = 0; nb < 2; nb++)
#pragma unroll
    for (int i = 0; i < 16; i++) oacc[nb][i] = 0.f;

  const int vc  = (tid & 7) * 8;
  const int vk0 = (tid >> 3) * 4;

  for (int t = 0; t < S_SZ / 128; t++) {
    __syncthreads();
    {
      const f16* gk = qkv + (tokbase + t * 128 + wave * 8 + su) * (size_t)rs + E_SZ + h * HD_SZ + soc * 8;
#pragma unroll
      for (int i = 0; i < 4; i++)
        async_ld16(gk + (size_t)i * 32 * rs, pool + (i * 32 + wave * 8) * 128);
    }
    {
      const bf16* gv = (const bf16*)qkv + (tokbase + t * 128 + vk0) * (size_t)rs + 2 * E_SZ + h * HD_SZ + vc;
      bf16x8 v0 = *(const bf16x8*)(gv);
      bf16x8 v1 = *(const bf16x8*)(gv + rs);
      bf16x8 v2 = *(const bf16x8*)(gv + 2 * rs);
      bf16x8 v3 = *(const bf16x8*)(gv + 3 * rs);
#pragma unroll
      for (int e = 0; e < 8; e++) {
        bf16x4 pk = {v0[e], v1[e], v2[e], v3[e]};
        *(bf16x4*)&Vt[(vc + e) * 132 + vk0] = pk;
      }
    }
    __syncthreads();

#pragma unroll
    for (int nt = 0; nt < 4; nt++) {
      f32x16 sacc;
#pragma unroll
      for (int i = 0; i < 16; i++) sacc[i] = 0.f;

      const int krow = nt * 32 + l31;
      __builtin_amdgcn_s_setprio(1);
#pragma unroll
      for (int ks = 0; ks < 4; ks++) {
        f16x8 kf = *(const f16x8*)&Ks[krow * 64 + (((ks * 2 + hi) ^ (krow & 7)) << 3)];
        sacc = __builtin_amdgcn_mfma_f32_32x32x16_f16(kf, aq[ks], sacc, 0, 0, 0);
      }
      __builtin_amdgcn_s_setprio(0);

      uint32_t w[8];
#pragma unroll
      for (int j = 0; j < 8; j++) {
        float p0 = exp2f(fmaf(sacc[2 * j],     scale2, -c2));
        float p1 = exp2f(fmaf(sacc[2 * j + 1], scale2, -c2));
        Lp += p0 + p1;
        bf16x2 pk2 = {(bf16)p0, (bf16)p1};
        w[j] = __builtin_bit_cast(uint32_t, pk2);
      }
      permswap(w[0], w[2]);
      permswap(w[1], w[3]);
      permswap(w[4], w[6]);
      permswap(w[5], w[7]);
      u32x4v pe = {w[0], w[1], w[2], w[3]};
      u32x4v po = {w[4], w[5], w[6], w[7]};
      bf16x8 pa[2] = {__builtin_bit_cast(bf16x8, pe), __builtin_bit_cast(bf16x8, po)};

      __builtin_amdgcn_s_setprio(1);
#pragma unroll
      for (int nb = 0; nb < 2; nb++) {
        const int d = nb * 32 + l31;
#pragma unroll
        for (int kst = 0; kst < 2; kst++) {
          const int key = (nt * 2 + kst) * 16 + hi * 8;
          bf16x4 blo = *(const bf16x4*)&Vt[d * 132 + key];
          bf16x4 bhi = *(const bf16x4*)&Vt[d * 132 + key + 4];
          bf16x8 bv = __builtin_shufflevector(blo, bhi, 0, 1, 2, 3, 4, 5, 6, 7);
          oacc[nb] = __builtin_amdgcn_mfma_f32_32x32x16_bf16(pa[kst], bv, oacc[nb], 0, 0, 0);
        }
      }
      __builtin_amdgcn_s_setprio(0);
    }
  }

  float Lfull = Lp + __shfl_xor(Lp, 32, 64);
  const float inv = 1.f / Lfull;
#pragma unroll
  for (int r = 0; r < 16; r++) {
    const int qrow = (r & 3) + 8 * (r >> 2) + 4 * hi;
    const float invr = __shfl(inv, qrow, 32);
    const size_t row = tokbase + (size_t)qt * 128 + wave * 32 + qrow;
#pragma unroll
    for (int nb = 0; nb < 2; nb++)
      ctx[row * (size_t)E_SZ + h * HD_SZ + nb * 32 + l31] = (f16)(oacc[nb][r] * invr);
  }
}

// ---------------------------------------------------------------------------
// LayerNorm(a + res) * g + b  over rows of 1024, fp32 (+optional f16 copy).
// ---------------------------------------------------------------------------
__global__ void ln_kernel(const float* __restrict__ a, const float* __restrict__ res,
                          const float* __restrict__ g, const float* __restrict__ bta,
                          float* __restrict__ out32, f16* __restrict__ out16) {
  const int row  = blockIdx.x;
  const int tid  = threadIdx.x;
  const int wave = tid >> 6;
  const int lane = tid & 63;
  const size_t base = (size_t)row * 1024;
  const int c = tid * 4;

  float4 va = *(const float4*)&a[base + c];
  float4 vr = *(const float4*)&res[base + c];
  float v0 = va.x + vr.x, v1 = va.y + vr.y, v2 = va.z + vr.z, v3 = va.w + vr.w;

  __shared__ float r1[4], r2[4];
  float s = v0 + v1 + v2 + v3;
#pragma unroll
  for (int off = 32; off; off >>= 1) s += __shfl_xor(s, off, 64);
  if (lane == 0) r1[wave] = s;
  __syncthreads();
  const float mu = (r1[0] + r1[1] + r1[2] + r1[3]) * (1.f / 1024.f);

  float d0 = v0 - mu, d1 = v1 - mu, d2 = v2 - mu, d3 = v3 - mu;
  float ss = d0 * d0 + d1 * d1 + d2 * d2 + d3 * d3;
#pragma unroll
  for (int off = 32; off; off >>= 1) ss += __shfl_xor(ss, off, 64);
  if (lane == 0) r2[wave] = ss;
  __syncthreads();
  const float var = (r2[0] + r2[1] + r2[2] + r2[3]) * (1.f / 1024.f);
  const float rsq = rsqrtf(var + 1e-5f);

  float4 gg = *(const float4*)&g[c];
  float4 bb = *(const float4*)&bta[c];
  float o0 = d0 * rsq * gg.x + bb.x;
  float o1 = d1 * rsq * gg.y + bb.y;
  float o2 = d2 * rsq * gg.z + bb.z;
  float o3 = d3 * rsq * gg.w + bb.w;
  float4 o = {o0, o1, o2, o3};
  *(float4*)&out32[base + c] = o;
  if (out16 != nullptr) {
    f16x4 ob = {(f16)o0, (f16)o1, (f16)o2, (f16)o3};
    *(f16x4*)&out16[base + c] = ob;
  }
}

// ---------------------------------------------------------------------------
// Launch
// ---------------------------------------------------------------------------
extern "C" void kernel_launch(void* const* d_in, const int* in_sizes, int n_in,
                              void* d_out, int out_size, void* d_ws, size_t ws_size,
                              hipStream_t stream) {
  const float* x    = (const float*)d_in[0];
  const float* wqkv = (const float*)d_in[1];
  const float* wo   = (const float*)d_in[2];
  const float* ln1g = (const float*)d_in[3];
  const float* ln1b = (const float*)d_in[4];
  const float* ln2g = (const float*)d_in[5];
  const float* ln2b = (const float*)d_in[6];
  const float* w1   = (const float*)d_in[7];
  const float* b1   = (const float*)d_in[8];
  const float* w2   = (const float*)d_in[9];
  const float* b2   = (const float*)d_in[10];
  float* out = (float*)d_out;

  char* ws = (char*)d_ws;
  f16* w_inb  = (f16*)(ws + 0);
  f16* w_outb = (f16*)(ws + 6291456);
  f16* w1b    = (f16*)(ws + 8388608);
  f16* w2b    = (f16*)(ws + 16777216);
  f16* xb     = (f16*)(ws + 25165824);
  f16* qkv    = (f16*)(ws + 41943040);   // q,k fp16 | v-third bf16
  f16* ctx    = (f16*)(ws + 92274688);
  f16* ff1    = (f16*)(ws + 41943040);
  float* tmp  = (float*)(ws + 109051904);
  float* hbuf = (float*)(ws + 142606336);
  f16* hb     = xb;

  const int NOBF = 1 << 30;

  cast_kernel<<<3072, 256, 0, stream>>>(wqkv, w_inb, 3 * E_SZ * E_SZ / 4);
  cast_kernel<<<1024, 256, 0, stream>>>(wo, w_outb, E_SZ * E_SZ / 4);
  cast_kernel<<<4096, 256, 0, stream>>>(w1, w1b, FF_SZ * E_SZ / 4);
  cast_kernel<<<4096, 256, 0, stream>>>(w2, w2b, E_SZ * FF_SZ / 4);
  cast_kernel<<<8192, 256, 0, stream>>>(x, xb, MTOK * E_SZ / 4);

  // qkv = x @ in_proj_w^T; V-third (cols >= 2048) stored bf16
  gemm256<256, true, false><<<(3 * E_SZ / 256) * (MTOK / 256), 512, 0, stream>>>(
      xb, w_inb, nullptr, qkv, MTOK, 3 * E_SZ, E_SZ, 2048);

  // p = 2^(2.5*dot - 60): 0.25*ln(1024)*log2(e) == 2.5 exactly
  attn_kernel<<<1024, 256, 0, stream>>>(qkv, ctx, 2.5f, 60.0f);

  gemm256<128, false, false><<<(E_SZ / 128) * (MTOK / 256), 512, 0, stream>>>(
      ctx, w_outb, nullptr, tmp, MTOK, E_SZ, E_SZ, NOBF);

  ln_kernel<<<MTOK, 256, 0, stream>>>(tmp, x, ln1g, ln1b, hbuf, hb);

  gemm256<256, true, true><<<(FF_SZ / 256) * (MTOK / 256), 512, 0, stream>>>(
      hb, w1b, b1, ff1, MTOK, FF_SZ, E_SZ, NOBF);

  gemm256<128, false, false><<<(E_SZ / 128) * (MTOK / 256), 512, 0, stream>>>(
      ff1, w2b, b2, tmp, MTOK, E_SZ, FF_SZ, NOBF);

  ln_kernel<<<MTOK, 256, 0, stream>>>(tmp, hbuf, ln2g, ln2b, out, nullptr);

  (void)in_sizes; (void)n_in; (void)out_size; (void)ws_size;
}

// Round 6
// 492.392 us; speedup vs baseline: 1.0228x; 1.0048x over previous
//
#include <hip/hip_runtime.h>
#include <cstdint>
#include <cmath>

// ---------------------------------------------------------------------------
// AttentionBlock: x -> MHA(custom scale) -> +res -> LN -> FFN -> +res -> LN
// B=8 S=1024 E=1024 H=16 HD=64 FF=4096, fp32 in/out, fp16 MFMA internally.
// v8: v7 with the BN=128 epilogue LDS overflow fixed (256x128 fp32 C-tile =
//     128 KB > the 96 KB BN=128 LDS; rows >=192 were dropped -> absmax 4.57).
//     fp32 outputs now use DIRECT f32x4 stores (swapped-operand layout makes
//     the 4 quads of one instruction cover 64 contiguous bytes per row --
//     granule-perfect, no staging needed).  f16 outputs (BN=256) keep the
//     LDS-staged coalesced epilogue (fits exactly: 131072 B).
//     K-loop schedule, super-tile map, attn/LN/cast identical to v7.
// ---------------------------------------------------------------------------

typedef _Float16 f16;
typedef _Float16 f16x8 __attribute__((ext_vector_type(8)));
typedef _Float16 f16x4 __attribute__((ext_vector_type(4)));
typedef __bf16   bf16;
typedef __bf16   bf16x8 __attribute__((ext_vector_type(8)));
typedef __bf16   bf16x4 __attribute__((ext_vector_type(4)));
typedef __bf16   bf16x2 __attribute__((ext_vector_type(2)));
typedef float    f32x4  __attribute__((ext_vector_type(4)));
typedef float    f32x16 __attribute__((ext_vector_type(16)));
typedef unsigned int uint2v __attribute__((ext_vector_type(2)));
typedef unsigned int u32x4v __attribute__((ext_vector_type(4)));

#define B_SZ  8
#define S_SZ  1024
#define E_SZ  1024
#define H_SZ  16
#define HD_SZ 64
#define FF_SZ 4096
#define MTOK  (B_SZ * S_SZ)   // 8192 tokens

// async global->LDS, 16B per lane.  LDS dest is wave-uniform base + lane*16.
__device__ __forceinline__ void async_ld16(const void* g, void* l) {
  __builtin_amdgcn_global_load_lds(
      (const __attribute__((address_space(1))) void*)(uintptr_t)g,
      (__attribute__((address_space(3))) void*)(uint32_t)(uintptr_t)l,
      16, 0, 0);
}

template <int N>
__device__ __forceinline__ void wait_vm() {
  if constexpr (N == 0)      asm volatile("s_waitcnt vmcnt(0)" ::: "memory");
  else if constexpr (N == 3) asm volatile("s_waitcnt vmcnt(3)" ::: "memory");
  else if constexpr (N == 4) asm volatile("s_waitcnt vmcnt(4)" ::: "memory");
  else static_assert(N == 0 || N == 3 || N == 4, "unsupported vmcnt");
  __builtin_amdgcn_sched_barrier(0);   // pin: nothing crosses the wait
}

__device__ __forceinline__ void wait_lgkm0_fenced() {
  asm volatile("s_waitcnt lgkmcnt(0)" ::: "memory");
  __builtin_amdgcn_sched_barrier(0);   // rule #18: keep MFMA below the wait
}

// swap a.lanes[32:63] <-> b.lanes[0:31]
__device__ __forceinline__ void permswap(uint32_t& a, uint32_t& b) {
  uint2v r = __builtin_amdgcn_permlane32_swap(a, b, false, false);
  a = r[0];
  b = r[1];
}

// ---------------------------------------------------------------------------
// fp32 -> fp16 cast (vectorized).
// ---------------------------------------------------------------------------
__global__ void cast_kernel(const float* __restrict__ in, f16* __restrict__ out, int n4) {
  int i = blockIdx.x * blockDim.x + threadIdx.x;
  if (i < n4) {
    float4 f = ((const float4*)in)[i];
    f16x4 o = {(f16)f.x, (f16)f.y, (f16)f.z, (f16)f.w};
    ((f16x4*)out)[i] = o;
  }
}

// ---------------------------------------------------------------------------
// C[M,N] = A[M,K] @ B[N,K]^T  (fp16, K contiguous), fp32 acc.
// Deep-pipelined 256-row tile, 8 waves (512 thr), double-buffered LDS.
// Swapped-operand MFMA: acc[mi][ni] = mfma(bfr[ni], af[mi], acc) ->
//   C row = ... + mi*16 + l16,  C col = ... + ni*16 + quad*4 + reg
// (reg dim = 4 consecutive columns -> vector epilogue stores).
// Block mapping: 4(bm) x 2(bn) super-tiles, one per XCD at a time.
// Epilogue: OUT_F16 (BN=256) -> LDS-staged coalesced dwordx4 stores;
//           fp32 (BN=128)    -> direct f32x4 stores (granule-perfect).
// ---------------------------------------------------------------------------
template <int BN, bool OUT_F16, bool RELU>
__global__ __launch_bounds__(512, 2)
void gemm256(const f16* __restrict__ A, const f16* __restrict__ Bm,
             const float* __restrict__ bias, void* __restrict__ Cp,
             int M, int N, int K, int bf16_from_col) {
  static_assert(BN == 256 || BN == 128, "BN must be 256 or 128");
  static_assert(!(OUT_F16 && BN == 128), "f16 LDS epilogue requires BN==256");
  constexpr int NBCH  = (BN == 256) ? 2 : 1;   // B row-halves (chunks) per slice
  constexpr int CHUNK = 4096;                  // f16 per 8 KB chunk: [128][32]
  constexpr int NIF   = 2 + NBCH;              // staging issues per K-slice
  constexpr int WN    = (BN == 256) ? 4 : 2;   // waves along N
  constexpr int FM    = (BN == 256) ? 8 : 4;   // M-fragments per wave

  __shared__ f16 lds[(8 + 4 * NBCH) * CHUNK];  // A: 8 chunks, B: 4*NBCH chunks
  f16* Ab = lds;                               // [buf][slice][half]*CHUNK
  f16* Bb = lds + 8 * CHUNK;

  const int tid  = threadIdx.x;
  const int wave = tid >> 6;
  const int lane = tid & 63;
  const int quad = lane >> 4;
  const int l16  = lane & 15;

  const int wm  = wave / WN;
  const int wn  = wave % WN;
  const int ah  = (BN == 256) ? wm : (wm >> 1);        // wave's A row-half
  const int amB = (BN == 256) ? 0 : (wm & 1) * 64;     // row base within half
  const int bh  = (BN == 256) ? (wn >> 1) : 0;         // wave's B row-half
  const int bnB = (BN == 256) ? (wn & 1) * 64 : wn * 64;

  // ---- L2-aware block decode: 4(bm) x 2(bn) super-tiles per XCD ----
  const int gx = N / BN;
  int bm, bn;
  {
    const int b   = blockIdx.x;
    const int nwg = gridDim.x;
    const int gm  = nwg / gx;
    if (((nwg & 63) == 0) && ((gx & 1) == 0) && ((gm & 3) == 0)) {
      const int xcd = b & 7;
      const int seq = b >> 3;
      const int st  = xcd + ((seq >> 3) << 3);   // super-tile id (bijective)
      const int pos = seq & 7;                   // 0..7 within 4x2 super-tile
      const int nstx = gx >> 1;
      bn = (st % nstx) * 2 + (pos & 1);
      bm = (st / nstx) * 4 + (pos >> 1);
    } else {
      int logical = b;
      if ((nwg & 7) == 0) logical = (logical & 7) * (nwg >> 3) + (logical >> 3);
      bn = logical % gx;
      bm = logical / gx;
    }
  }

  f32x4 acc[FM][4];
#pragma unroll
  for (int mi = 0; mi < FM; mi++)
#pragma unroll
    for (int ni = 0; ni < 4; ni++) acc[mi][ni] = (f32x4){0.f, 0.f, 0.f, 0.f};

  // staging thread params: thread covers chunk row rr_s, physical octet tid&3,
  // holding logical octet lo_s = (tid&3) ^ ((rr_s>>1)&3).
  const int rr_s = tid >> 2;
  const int lo_s = (tid & 3) ^ ((rr_s >> 1) & 3);
  const int wofs = wave * 512;   // wave's 1 KB slot inside a chunk (f16 units)
  const f16* gAb = A  + ((size_t)bm * 256 + rr_s) * (size_t)K + lo_s * 8;
  const f16* gBb = Bm + ((size_t)bn * BN  + rr_s) * (size_t)K + lo_s * 8;

  auto stA = [&](int bb, int s, int h, int kt) {
    async_ld16(gAb + (size_t)h * 128 * K + kt * 64 + s * 32,
               Ab + ((((bb << 1) + s) << 1) + h) * CHUNK + wofs);
  };
  auto stB = [&](int bb, int s, int h, int kt) {
    async_ld16(gBb + (size_t)h * 128 * K + kt * 64 + s * 32,
               Bb + (((bb << 1) + s) * NBCH + h) * CHUNK + wofs);
  };
  auto rdFrag = [&](const f16* ch, int rr) -> f16x8 {
    return *(const f16x8*)&ch[rr * 32 + ((quad ^ ((rr >> 1) & 3)) << 3)];
  };

  const int NT = K >> 6;

  // ---- prologue: stage tile 0 (slice 0 then slice 1) into buf 0 ----
#pragma unroll
  for (int s = 0; s < 2; s++) {
    stA(0, s, 0, 0);
    stA(0, s, 1, 0);
    stB(0, s, 0, 0);
    if constexpr (NBCH == 2) stB(0, s, 1, 0);
  }
  wait_vm<NIF>();                       // tile0 slice0 complete, slice1 in flight
  __builtin_amdgcn_s_barrier();

  for (int t = 0; t < NT; t++) {
    const int cur = t & 1, oth = cur ^ 1;
    const bool last = (t == NT - 1);
#pragma unroll
    for (int s = 0; s < 2; s++) {
      const f16* Ach = Ab + ((((cur << 1) + s) << 1) + ah) * CHUNK;
      const f16* Bch = Bb + (((cur << 1) + s) * NBCH + bh) * CHUNK;

      // ---- phase A: reads + stage issues BEFORE the barrier ----
      f16x8 bfr[4], af[4];
#pragma unroll
      for (int ni = 0; ni < 4; ni++) bfr[ni] = rdFrag(Bch, bnB + ni * 16 + l16);
#pragma unroll
      for (int i = 0; i < 4; i++) af[i] = rdFrag(Ach, amB + i * 16 + l16);
      if (!last) {
        stA(oth, s, 0, t + 1);
        stA(oth, s, 1, t + 1);
        if constexpr (NBCH == 1) stB(oth, s, 0, t + 1);
      }
      __builtin_amdgcn_sched_barrier(0);
      __builtin_amdgcn_s_barrier();
      wait_lgkm0_fenced();
      __builtin_amdgcn_s_setprio(1);
#pragma unroll
      for (int i = 0; i < 4; i++)
#pragma unroll
        for (int ni = 0; ni < 4; ni++)
          acc[i][ni] = __builtin_amdgcn_mfma_f32_16x16x32_f16(bfr[ni], af[i], acc[i][ni], 0, 0, 0);
      __builtin_amdgcn_s_setprio(0);

      if constexpr (BN == 256) {
        // ---- phase B: second m-half, B-frags still live ----
        __builtin_amdgcn_s_barrier();
#pragma unroll
        for (int i = 0; i < 4; i++) af[i] = rdFrag(Ach, amB + (4 + i) * 16 + l16);
        if (!last) {
          stB(oth, s, 0, t + 1);
          stB(oth, s, 1, t + 1);
        }
        __builtin_amdgcn_sched_barrier(0);
        __builtin_amdgcn_s_barrier();
        wait_lgkm0_fenced();
        __builtin_amdgcn_s_setprio(1);
#pragma unroll
        for (int i = 0; i < 4; i++)
#pragma unroll
          for (int ni = 0; ni < 4; ni++)
            acc[4 + i][ni] = __builtin_amdgcn_mfma_f32_16x16x32_f16(bfr[ni], af[i], acc[4 + i][ni], 0, 0, 0);
        __builtin_amdgcn_s_setprio(0);
      }

      // ---- slice boundary: make the next-needed slice visible ----
      if (!last) {
        wait_vm<NIF>();                 // oldest NIF (next slice's chunks) done
        __builtin_amdgcn_s_barrier();
      } else if (s == 0) {
        wait_vm<0>();                   // final drain: last tile's slice 1
        __builtin_amdgcn_s_barrier();
      }
    }
  }

  // ---- epilogue ----
  // Swapped-mfma C map: row = block_row + mi*16 + l16,
  //                     col = block_col + ni*16 + quad*4 + reg.
  if constexpr (!OUT_F16) {
    // Direct f32x4 stores: 4 quads of one instruction = 64 contiguous bytes
    // per row -> granule-perfect, no LDS needed (fixes v7's LDS overflow).
    const int rowG0 = bm * 256 + ((BN == 256) ? wm * 128 : wm * 64);
    const int colG0 = bn * BN + wn * 64;
    float* Cf = (float*)Cp;
#pragma unroll
    for (int ni = 0; ni < 4; ni++) {
      const int col = colG0 + ni * 16 + quad * 4;
      float4 bv = {0.f, 0.f, 0.f, 0.f};
      if (bias != nullptr) bv = *(const float4*)&bias[col];
#pragma unroll
      for (int mi = 0; mi < FM; mi++) {
        const int row = rowG0 + mi * 16 + l16;
        float v0 = acc[mi][ni][0] + bv.x;
        float v1 = acc[mi][ni][1] + bv.y;
        float v2 = acc[mi][ni][2] + bv.z;
        float v3 = acc[mi][ni][3] + bv.w;
        if (RELU) {
          v0 = fmaxf(v0, 0.f); v1 = fmaxf(v1, 0.f);
          v2 = fmaxf(v2, 0.f); v3 = fmaxf(v3, 0.f);
        }
        f32x4 o = {v0, v1, v2, v3};
        *(f32x4*)&Cf[(size_t)row * N + col] = o;
      }
    }
  } else {
    // LDS-staged coalesced epilogue (BN=256 only; 256 rows x 512 B = 128 KB
    // fits the 131072-B K-loop LDS exactly).
    __syncthreads();   // all waves done reading K-loop chunks
    {
      char* cb = (char*)lds;
      const int rowL0 = wm * 128;
      const int colL0 = wn * 64;
      const bool store_bf16 = (bn * BN >= bf16_from_col);
#pragma unroll
      for (int mi = 0; mi < FM; mi++) {
        const int row = rowL0 + mi * 16 + l16;
        const int sw  = row & 7;
#pragma unroll
        for (int ni = 0; ni < 4; ni++) {
          const int col = colL0 + ni * 16 + quad * 4;   // local col of reg 0
          float4 bv = {0.f, 0.f, 0.f, 0.f};
          if (bias != nullptr) bv = *(const float4*)&bias[bn * BN + col];
          float v0 = acc[mi][ni][0] + bv.x;
          float v1 = acc[mi][ni][1] + bv.y;
          float v2 = acc[mi][ni][2] + bv.z;
          float v3 = acc[mi][ni][3] + bv.w;
          if (RELU) {
            v0 = fmaxf(v0, 0.f); v1 = fmaxf(v1, 0.f);
            v2 = fmaxf(v2, 0.f); v3 = fmaxf(v3, 0.f);
          }
          const int ch = (col >> 3) ^ sw;               // 16-B chunk swizzle
          char* p = cb + row * 512 + (ch << 4) + ((quad & 1) << 3);
          if (store_bf16) {
            bf16x4 o = {(bf16)v0, (bf16)v1, (bf16)v2, (bf16)v3};
            *(bf16x4*)p = o;
          } else {
            f16x4 o = {(f16)v0, (f16)v1, (f16)v2, (f16)v3};
            *(f16x4*)p = o;
          }
        }
      }
    }
    __syncthreads();
    {
      const char* cb = (const char*)lds;
      const int rr0 = tid >> 5;          // 0..15
      const int cc  = tid & 31;          // 16-B chunk within the 512-B row
      const size_t rowBytes = (size_t)N * 2;
      char* gbase = (char*)Cp + (size_t)(bm * 256) * rowBytes
                  + (size_t)bn * BN * 2 + (size_t)cc * 16;
#pragma unroll
      for (int it = 0; it < 16; it++) {
        const int row = it * 16 + rr0;
        const int ch  = cc ^ (row & 7);
        u32x4v v = *(const u32x4v*)(cb + row * 512 + (ch << 4));
        *(u32x4v*)(gbase + (size_t)row * rowBytes) = v;
      }
    }
  }
  (void)M;
}

// ---------------------------------------------------------------------------
// Fused flash attention v4 (32x32x16 MFMA) -- unchanged (round-1 passing).
// ---------------------------------------------------------------------------
__global__ __launch_bounds__(256, 4)
void attn_kernel(const f16* __restrict__ qkv, f16* __restrict__ ctx,
                 float scale2, float c2) {
  __shared__ __align__(16) char pool[33280];
  f16*  Ks = (f16*)pool;              // [key 0..127] x 64 f16, XOR-octet swizzle; Q preload overlays
  bf16* Vt = (bf16*)(pool + 16384);   // [d 0..63] stride 132 bf16

  const int tid  = threadIdx.x;
  const int wave = tid >> 6;
  const int lane = tid & 63;
  const int l31  = lane & 31;
  const int hi   = lane >> 5;

  const int flat = blockIdx.x;
  const int bh   = flat & 127;
  const int qt   = flat >> 7;
  const int b    = bh >> 4;
  const int h    = bh & 15;

  const int rs = 3 * E_SZ;
  const size_t tokbase = (size_t)b * S_SZ;

  const int su  = lane >> 3;
  const int soc = (lane & 7) ^ su;

  {
    const f16* gq = qkv + (tokbase + qt * 128 + wave * 8 + su) * (size_t)rs + h * HD_SZ + soc * 8;
#pragma unroll
    for (int i = 0; i < 4; i++)
      async_ld16(gq + (size_t)i * 32 * rs, pool + (i * 32 + wave * 8) * 128);
  }
  __syncthreads();

  f16x8 aq[4];
  {
    const int qrow = wave * 32 + l31;
#pragma unroll
    for (int ks = 0; ks < 4; ks++)
      aq[ks] = *(const f16x8*)&Ks[qrow * 64 + (((ks * 2 + hi) ^ (qrow & 7)) << 3)];
  }

  float Lp = 0.f;
  f32x16 oacc[2];
#pragma unroll
  for (int nb = 0; nb < 2; nb++)
#pragma unroll
    for (int i = 0; i < 16; i++) oacc[nb][i] = 0.f;

  const int vc  = (tid & 7) * 8;
  const int vk0 = (tid >> 3) * 4;

  for (int t = 0; t < S_SZ / 128; t++) {
    __syncthreads();
    {
      const f16* gk = qkv + (tokbase + t * 128 + wave * 8 + su) * (size_t)rs + E_SZ + h * HD_SZ + soc * 8;
#pragma unroll
      for (int i = 0; i < 4; i++)
        async_ld16(gk + (size_t)i * 32 * rs, pool + (i * 32 + wave * 8) * 128);
    }
    {
      const bf16* gv = (const bf16*)qkv + (tokbase + t * 128 + vk0) * (size_t)rs + 2 * E_SZ + h * HD_SZ + vc;
      bf16x8 v0 = *(const bf16x8*)(gv);
      bf16x8 v1 = *(const bf16x8*)(gv + rs);
      bf16x8 v2 = *(const bf16x8*)(gv + 2 * rs);
      bf16x8 v3 = *(const bf16x8*)(gv + 3 * rs);
#pragma unroll
      for (int e = 0; e < 8; e++) {
        bf16x4 pk = {v0[e], v1[e], v2[e], v3[e]};
        *(bf16x4*)&Vt[(vc + e) * 132 + vk0] = pk;
      }
    }
    __syncthreads();

#pragma unroll
    for (int nt = 0; nt < 4; nt++) {
      f32x16 sacc;
#pragma unroll
      for (int i = 0; i < 16; i++) sacc[i] = 0.f;

      const int krow = nt * 32 + l31;
      __builtin_amdgcn_s_setprio(1);
#pragma unroll
      for (int ks = 0; ks < 4; ks++) {
        f16x8 kf = *(const f16x8*)&Ks[krow * 64 + (((ks * 2 + hi) ^ (krow & 7)) << 3)];
        sacc = __builtin_amdgcn_mfma_f32_32x32x16_f16(kf, aq[ks], sacc, 0, 0, 0);
      }
      __builtin_amdgcn_s_setprio(0);

      uint32_t w[8];
#pragma unroll
      for (int j = 0; j < 8; j++) {
        float p0 = exp2f(fmaf(sacc[2 * j],     scale2, -c2));
        float p1 = exp2f(fmaf(sacc[2 * j + 1], scale2, -c2));
        Lp += p0 + p1;
        bf16x2 pk2 = {(bf16)p0, (bf16)p1};
        w[j] = __builtin_bit_cast(uint32_t, pk2);
      }
      permswap(w[0], w[2]);
      permswap(w[1], w[3]);
      permswap(w[4], w[6]);
      permswap(w[5], w[7]);
      u32x4v pe = {w[0], w[1], w[2], w[3]};
      u32x4v po = {w[4], w[5], w[6], w[7]};
      bf16x8 pa[2] = {__builtin_bit_cast(bf16x8, pe), __builtin_bit_cast(bf16x8, po)};

      __builtin_amdgcn_s_setprio(1);
#pragma unroll
      for (int nb = 0; nb < 2; nb++) {
        const int d = nb * 32 + l31;
#pragma unroll
        for (int kst = 0; kst < 2; kst++) {
          const int key = (nt * 2 + kst) * 16 + hi * 8;
          bf16x4 blo = *(const bf16x4*)&Vt[d * 132 + key];
          bf16x4 bhi = *(const bf16x4*)&Vt[d * 132 + key + 4];
          bf16x8 bv = __builtin_shufflevector(blo, bhi, 0, 1, 2, 3, 4, 5, 6, 7);
          oacc[nb] = __builtin_amdgcn_mfma_f32_32x32x16_bf16(pa[kst], bv, oacc[nb], 0, 0, 0);
        }
      }
      __builtin_amdgcn_s_setprio(0);
    }
  }

  float Lfull = Lp + __shfl_xor(Lp, 32, 64);
  const float inv = 1.f / Lfull;
#pragma unroll
  for (int r = 0; r < 16; r++) {
    const int qrow = (r & 3) + 8 * (r >> 2) + 4 * hi;
    const float invr = __shfl(inv, qrow, 32);
    const size_t row = tokbase + (size_t)qt * 128 + wave * 32 + qrow;
#pragma unroll
    for (int nb = 0; nb < 2; nb++)
      ctx[row * (size_t)E_SZ + h * HD_SZ + nb * 32 + l31] = (f16)(oacc[nb][r] * invr);
  }
}

// ---------------------------------------------------------------------------
// LayerNorm(a + res) * g + b  over rows of 1024, fp32 (+optional f16 copy).
// ---------------------------------------------------------------------------
__global__ void ln_kernel(const float* __restrict__ a, const float* __restrict__ res,
                          const float* __restrict__ g, const float* __restrict__ bta,
                          float* __restrict__ out32, f16* __restrict__ out16) {
  const int row  = blockIdx.x;
  const int tid  = threadIdx.x;
  const int wave = tid >> 6;
  const int lane = tid & 63;
  const size_t base = (size_t)row * 1024;
  const int c = tid * 4;

  float4 va = *(const float4*)&a[base + c];
  float4 vr = *(const float4*)&res[base + c];
  float v0 = va.x + vr.x, v1 = va.y + vr.y, v2 = va.z + vr.z, v3 = va.w + vr.w;

  __shared__ float r1[4], r2[4];
  float s = v0 + v1 + v2 + v3;
#pragma unroll
  for (int off = 32; off; off >>= 1) s += __shfl_xor(s, off, 64);
  if (lane == 0) r1[wave] = s;
  __syncthreads();
  const float mu = (r1[0] + r1[1] + r1[2] + r1[3]) * (1.f / 1024.f);

  float d0 = v0 - mu, d1 = v1 - mu, d2 = v2 - mu, d3 = v3 - mu;
  float ss = d0 * d0 + d1 * d1 + d2 * d2 + d3 * d3;
#pragma unroll
  for (int off = 32; off; off >>= 1) ss += __shfl_xor(ss, off, 64);
  if (lane == 0) r2[wave] = ss;
  __syncthreads();
  const float var = (r2[0] + r2[1] + r2[2] + r2[3]) * (1.f / 1024.f);
  const float rsq = rsqrtf(var + 1e-5f);

  float4 gg = *(const float4*)&g[c];
  float4 bb = *(const float4*)&bta[c];
  float o0 = d0 * rsq * gg.x + bb.x;
  float o1 = d1 * rsq * gg.y + bb.y;
  float o2 = d2 * rsq * gg.z + bb.z;
  float o3 = d3 * rsq * gg.w + bb.w;
  float4 o = {o0, o1, o2, o3};
  *(float4*)&out32[base + c] = o;
  if (out16 != nullptr) {
    f16x4 ob = {(f16)o0, (f16)o1, (f16)o2, (f16)o3};
    *(f16x4*)&out16[base + c] = ob;
  }
}

// ---------------------------------------------------------------------------
// Launch
// ---------------------------------------------------------------------------
extern "C" void kernel_launch(void* const* d_in, const int* in_sizes, int n_in,
                              void* d_out, int out_size, void* d_ws, size_t ws_size,
                              hipStream_t stream) {
  const float* x    = (const float*)d_in[0];
  const float* wqkv = (const float*)d_in[1];
  const float* wo   = (const float*)d_in[2];
  const float* ln1g = (const float*)d_in[3];
  const float* ln1b = (const float*)d_in[4];
  const float* ln2g = (const float*)d_in[5];
  const float* ln2b = (const float*)d_in[6];
  const float* w1   = (const float*)d_in[7];
  const float* b1   = (const float*)d_in[8];
  const float* w2   = (const float*)d_in[9];
  const float* b2   = (const float*)d_in[10];
  float* out = (float*)d_out;

  char* ws = (char*)d_ws;
  f16* w_inb  = (f16*)(ws + 0);
  f16* w_outb = (f16*)(ws + 6291456);
  f16* w1b    = (f16*)(ws + 8388608);
  f16* w2b    = (f16*)(ws + 16777216);
  f16* xb     = (f16*)(ws + 25165824);
  f16* qkv    = (f16*)(ws + 41943040);   // q,k fp16 | v-third bf16
  f16* ctx    = (f16*)(ws + 92274688);
  f16* ff1    = (f16*)(ws + 41943040);
  float* tmp  = (float*)(ws + 109051904);
  float* hbuf = (float*)(ws + 142606336);
  f16* hb     = xb;

  const int NOBF = 1 << 30;

  cast_kernel<<<3072, 256, 0, stream>>>(wqkv, w_inb, 3 * E_SZ * E_SZ / 4);
  cast_kernel<<<1024, 256, 0, stream>>>(wo, w_outb, E_SZ * E_SZ / 4);
  cast_kernel<<<4096, 256, 0, stream>>>(w1, w1b, FF_SZ * E_SZ / 4);
  cast_kernel<<<4096, 256, 0, stream>>>(w2, w2b, E_SZ * FF_SZ / 4);
  cast_kernel<<<8192, 256, 0, stream>>>(x, xb, MTOK * E_SZ / 4);

  // qkv = x @ in_proj_w^T; V-third (cols >= 2048) stored bf16
  gemm256<256, true, false><<<(3 * E_SZ / 256) * (MTOK / 256), 512, 0, stream>>>(
      xb, w_inb, nullptr, qkv, MTOK, 3 * E_SZ, E_SZ, 2048);

  // p = 2^(2.5*dot - 60): 0.25*ln(1024)*log2(e) == 2.5 exactly
  attn_kernel<<<1024, 256, 0, stream>>>(qkv, ctx, 2.5f, 60.0f);

  gemm256<128, false, false><<<(E_SZ / 128) * (MTOK / 256), 512, 0, stream>>>(
      ctx, w_outb, nullptr, tmp, MTOK, E_SZ, E_SZ, NOBF);

  ln_kernel<<<MTOK, 256, 0, stream>>>(tmp, x, ln1g, ln1b, hbuf, hb);

  gemm256<256, true, true><<<(FF_SZ / 256) * (MTOK / 256), 512, 0, stream>>>(
      hb, w1b, b1, ff1, MTOK, FF_SZ, E_SZ, NOBF);

  gemm256<128, false, false><<<(E_SZ / 128) * (MTOK / 256), 512, 0, stream>>>(
      ff1, w2b, b2, tmp, MTOK, E_SZ, FF_SZ, NOBF);

  ln_kernel<<<MTOK, 256, 0, stream>>>(tmp, hbuf, ln2g, ln2b, out, nullptr);

  (void)in_sizes; (void)n_in; (void)out_size; (void)ws_size;
}

// Round 7
// 481.891 us; speedup vs baseline: 1.0450x; 1.0218x over previous
//
#include <hip/hip_runtime.h>
#include <cstdint>
#include <cmath>

// ---------------------------------------------------------------------------
// AttentionBlock: x -> MHA(custom scale) -> +res -> LN -> FFN -> +res -> LN
// B=8 S=1024 E=1024 H=16 HD=64 FF=4096, fp32 in/out, fp16 MFMA internally.
// v9: v8 + the 5 fp32->f16 cast kernels fused into ONE segmented kernel
//     (launch count 12 -> 8; tests the launch-gap theory: ~110 us of the
//     total is unaccounted between kernels).  GEMM/attn/LN byte-identical
//     to the round-6 passing build.
// ---------------------------------------------------------------------------

typedef _Float16 f16;
typedef _Float16 f16x8 __attribute__((ext_vector_type(8)));
typedef _Float16 f16x4 __attribute__((ext_vector_type(4)));
typedef __bf16   bf16;
typedef __bf16   bf16x8 __attribute__((ext_vector_type(8)));
typedef __bf16   bf16x4 __attribute__((ext_vector_type(4)));
typedef __bf16   bf16x2 __attribute__((ext_vector_type(2)));
typedef float    f32x4  __attribute__((ext_vector_type(4)));
typedef float    f32x16 __attribute__((ext_vector_type(16)));
typedef unsigned int uint2v __attribute__((ext_vector_type(2)));
typedef unsigned int u32x4v __attribute__((ext_vector_type(4)));

#define B_SZ  8
#define S_SZ  1024
#define E_SZ  1024
#define H_SZ  16
#define HD_SZ 64
#define FF_SZ 4096
#define MTOK  (B_SZ * S_SZ)   // 8192 tokens

// async global->LDS, 16B per lane.  LDS dest is wave-uniform base + lane*16.
__device__ __forceinline__ void async_ld16(const void* g, void* l) {
  __builtin_amdgcn_global_load_lds(
      (const __attribute__((address_space(1))) void*)(uintptr_t)g,
      (__attribute__((address_space(3))) void*)(uint32_t)(uintptr_t)l,
      16, 0, 0);
}

template <int N>
__device__ __forceinline__ void wait_vm() {
  if constexpr (N == 0)      asm volatile("s_waitcnt vmcnt(0)" ::: "memory");
  else if constexpr (N == 3) asm volatile("s_waitcnt vmcnt(3)" ::: "memory");
  else if constexpr (N == 4) asm volatile("s_waitcnt vmcnt(4)" ::: "memory");
  else static_assert(N == 0 || N == 3 || N == 4, "unsupported vmcnt");
  __builtin_amdgcn_sched_barrier(0);   // pin: nothing crosses the wait
}

__device__ __forceinline__ void wait_lgkm0_fenced() {
  asm volatile("s_waitcnt lgkmcnt(0)" ::: "memory");
  __builtin_amdgcn_sched_barrier(0);   // rule #18: keep MFMA below the wait
}

// swap a.lanes[32:63] <-> b.lanes[0:31]
__device__ __forceinline__ void permswap(uint32_t& a, uint32_t& b) {
  uint2v r = __builtin_amdgcn_permlane32_swap(a, b, false, false);
  a = r[0];
  b = r[1];
}

// ---------------------------------------------------------------------------
// Fused fp32 -> fp16 cast for all 5 tensors (one launch).
// Segment boundaries in float4 units (compile-time):
//   wqkv 786432 | wo 262144 | w1 1048576 | w2 1048576 | x 2097152
// Total 5242880 float4 = 20480 blocks x 256 threads exactly.
// ---------------------------------------------------------------------------
__global__ void cast_all_kernel(const float* __restrict__ wqkv, const float* __restrict__ wo,
                                const float* __restrict__ w1, const float* __restrict__ w2,
                                const float* __restrict__ x,
                                f16* __restrict__ w_inb, f16* __restrict__ w_outb,
                                f16* __restrict__ w1b, f16* __restrict__ w2b,
                                f16* __restrict__ xb) {
  const int i = blockIdx.x * blockDim.x + threadIdx.x;
  const float* src;
  f16* dst;
  int off;
  if (i < 786432)       { src = wqkv; dst = w_inb;  off = i; }
  else if (i < 1048576) { src = wo;   dst = w_outb; off = i - 786432; }
  else if (i < 2097152) { src = w1;   dst = w1b;    off = i - 1048576; }
  else if (i < 3145728) { src = w2;   dst = w2b;    off = i - 2097152; }
  else                  { src = x;    dst = xb;     off = i - 3145728; }
  float4 f = ((const float4*)src)[off];
  f16x4 o = {(f16)f.x, (f16)f.y, (f16)f.z, (f16)f.w};
  ((f16x4*)dst)[off] = o;
}

// ---------------------------------------------------------------------------
// C[M,N] = A[M,K] @ B[N,K]^T  (fp16, K contiguous), fp32 acc.
// Deep-pipelined 256-row tile, 8 waves (512 thr), double-buffered LDS.
// Swapped-operand MFMA: acc[mi][ni] = mfma(bfr[ni], af[mi], acc) ->
//   C row = ... + mi*16 + l16,  C col = ... + ni*16 + quad*4 + reg
// (reg dim = 4 consecutive columns -> vector epilogue stores).
// Block mapping: 4(bm) x 2(bn) super-tiles, one per XCD at a time.
// Epilogue: OUT_F16 (BN=256) -> LDS-staged coalesced dwordx4 stores;
//           fp32 (BN=128)    -> direct f32x4 stores (granule-perfect).
// ---------------------------------------------------------------------------
template <int BN, bool OUT_F16, bool RELU>
__global__ __launch_bounds__(512, 2)
void gemm256(const f16* __restrict__ A, const f16* __restrict__ Bm,
             const float* __restrict__ bias, void* __restrict__ Cp,
             int M, int N, int K, int bf16_from_col) {
  static_assert(BN == 256 || BN == 128, "BN must be 256 or 128");
  static_assert(!(OUT_F16 && BN == 128), "f16 LDS epilogue requires BN==256");
  constexpr int NBCH  = (BN == 256) ? 2 : 1;   // B row-halves (chunks) per slice
  constexpr int CHUNK = 4096;                  // f16 per 8 KB chunk: [128][32]
  constexpr int NIF   = 2 + NBCH;              // staging issues per K-slice
  constexpr int WN    = (BN == 256) ? 4 : 2;   // waves along N
  constexpr int FM    = (BN == 256) ? 8 : 4;   // M-fragments per wave

  __shared__ f16 lds[(8 + 4 * NBCH) * CHUNK];  // A: 8 chunks, B: 4*NBCH chunks
  f16* Ab = lds;                               // [buf][slice][half]*CHUNK
  f16* Bb = lds + 8 * CHUNK;

  const int tid  = threadIdx.x;
  const int wave = tid >> 6;
  const int lane = tid & 63;
  const int quad = lane >> 4;
  const int l16  = lane & 15;

  const int wm  = wave / WN;
  const int wn  = wave % WN;
  const int ah  = (BN == 256) ? wm : (wm >> 1);        // wave's A row-half
  const int amB = (BN == 256) ? 0 : (wm & 1) * 64;     // row base within half
  const int bh  = (BN == 256) ? (wn >> 1) : 0;         // wave's B row-half
  const int bnB = (BN == 256) ? (wn & 1) * 64 : wn * 64;

  // ---- L2-aware block decode: 4(bm) x 2(bn) super-tiles per XCD ----
  const int gx = N / BN;
  int bm, bn;
  {
    const int b   = blockIdx.x;
    const int nwg = gridDim.x;
    const int gm  = nwg / gx;
    if (((nwg & 63) == 0) && ((gx & 1) == 0) && ((gm & 3) == 0)) {
      const int xcd = b & 7;
      const int seq = b >> 3;
      const int st  = xcd + ((seq >> 3) << 3);   // super-tile id (bijective)
      const int pos = seq & 7;                   // 0..7 within 4x2 super-tile
      const int nstx = gx >> 1;
      bn = (st % nstx) * 2 + (pos & 1);
      bm = (st / nstx) * 4 + (pos >> 1);
    } else {
      int logical = b;
      if ((nwg & 7) == 0) logical = (logical & 7) * (nwg >> 3) + (logical >> 3);
      bn = logical % gx;
      bm = logical / gx;
    }
  }

  f32x4 acc[FM][4];
#pragma unroll
  for (int mi = 0; mi < FM; mi++)
#pragma unroll
    for (int ni = 0; ni < 4; ni++) acc[mi][ni] = (f32x4){0.f, 0.f, 0.f, 0.f};

  // staging thread params: thread covers chunk row rr_s, physical octet tid&3,
  // holding logical octet lo_s = (tid&3) ^ ((rr_s>>1)&3).
  const int rr_s = tid >> 2;
  const int lo_s = (tid & 3) ^ ((rr_s >> 1) & 3);
  const int wofs = wave * 512;   // wave's 1 KB slot inside a chunk (f16 units)
  const f16* gAb = A  + ((size_t)bm * 256 + rr_s) * (size_t)K + lo_s * 8;
  const f16* gBb = Bm + ((size_t)bn * BN  + rr_s) * (size_t)K + lo_s * 8;

  auto stA = [&](int bb, int s, int h, int kt) {
    async_ld16(gAb + (size_t)h * 128 * K + kt * 64 + s * 32,
               Ab + ((((bb << 1) + s) << 1) + h) * CHUNK + wofs);
  };
  auto stB = [&](int bb, int s, int h, int kt) {
    async_ld16(gBb + (size_t)h * 128 * K + kt * 64 + s * 32,
               Bb + (((bb << 1) + s) * NBCH + h) * CHUNK + wofs);
  };
  auto rdFrag = [&](const f16* ch, int rr) -> f16x8 {
    return *(const f16x8*)&ch[rr * 32 + ((quad ^ ((rr >> 1) & 3)) << 3)];
  };

  const int NT = K >> 6;

  // ---- prologue: stage tile 0 (slice 0 then slice 1) into buf 0 ----
#pragma unroll
  for (int s = 0; s < 2; s++) {
    stA(0, s, 0, 0);
    stA(0, s, 1, 0);
    stB(0, s, 0, 0);
    if constexpr (NBCH == 2) stB(0, s, 1, 0);
  }
  wait_vm<NIF>();                       // tile0 slice0 complete, slice1 in flight
  __builtin_amdgcn_s_barrier();

  for (int t = 0; t < NT; t++) {
    const int cur = t & 1, oth = cur ^ 1;
    const bool last = (t == NT - 1);
#pragma unroll
    for (int s = 0; s < 2; s++) {
      const f16* Ach = Ab + ((((cur << 1) + s) << 1) + ah) * CHUNK;
      const f16* Bch = Bb + (((cur << 1) + s) * NBCH + bh) * CHUNK;

      // ---- phase A: reads + stage issues BEFORE the barrier ----
      f16x8 bfr[4], af[4];
#pragma unroll
      for (int ni = 0; ni < 4; ni++) bfr[ni] = rdFrag(Bch, bnB + ni * 16 + l16);
#pragma unroll
      for (int i = 0; i < 4; i++) af[i] = rdFrag(Ach, amB + i * 16 + l16);
      if (!last) {
        stA(oth, s, 0, t + 1);
        stA(oth, s, 1, t + 1);
        if constexpr (NBCH == 1) stB(oth, s, 0, t + 1);
      }
      __builtin_amdgcn_sched_barrier(0);
      __builtin_amdgcn_s_barrier();
      wait_lgkm0_fenced();
      __builtin_amdgcn_s_setprio(1);
#pragma unroll
      for (int i = 0; i < 4; i++)
#pragma unroll
        for (int ni = 0; ni < 4; ni++)
          acc[i][ni] = __builtin_amdgcn_mfma_f32_16x16x32_f16(bfr[ni], af[i], acc[i][ni], 0, 0, 0);
      __builtin_amdgcn_s_setprio(0);

      if constexpr (BN == 256) {
        // ---- phase B: second m-half, B-frags still live ----
        __builtin_amdgcn_s_barrier();
#pragma unroll
        for (int i = 0; i < 4; i++) af[i] = rdFrag(Ach, amB + (4 + i) * 16 + l16);
        if (!last) {
          stB(oth, s, 0, t + 1);
          stB(oth, s, 1, t + 1);
        }
        __builtin_amdgcn_sched_barrier(0);
        __builtin_amdgcn_s_barrier();
        wait_lgkm0_fenced();
        __builtin_amdgcn_s_setprio(1);
#pragma unroll
        for (int i = 0; i < 4; i++)
#pragma unroll
          for (int ni = 0; ni < 4; ni++)
            acc[4 + i][ni] = __builtin_amdgcn_mfma_f32_16x16x32_f16(bfr[ni], af[i], acc[4 + i][ni], 0, 0, 0);
        __builtin_amdgcn_s_setprio(0);
      }

      // ---- slice boundary: make the next-needed slice visible ----
      if (!last) {
        wait_vm<NIF>();                 // oldest NIF (next slice's chunks) done
        __builtin_amdgcn_s_barrier();
      } else if (s == 0) {
        wait_vm<0>();                   // final drain: last tile's slice 1
        __builtin_amdgcn_s_barrier();
      }
    }
  }

  // ---- epilogue ----
  // Swapped-mfma C map: row = block_row + mi*16 + l16,
  //                     col = block_col + ni*16 + quad*4 + reg.
  if constexpr (!OUT_F16) {
    // Direct f32x4 stores: 4 quads of one instruction = 64 contiguous bytes
    // per row -> granule-perfect, no LDS needed.
    const int rowG0 = bm * 256 + ((BN == 256) ? wm * 128 : wm * 64);
    const int colG0 = bn * BN + wn * 64;
    float* Cf = (float*)Cp;
#pragma unroll
    for (int ni = 0; ni < 4; ni++) {
      const int col = colG0 + ni * 16 + quad * 4;
      float4 bv = {0.f, 0.f, 0.f, 0.f};
      if (bias != nullptr) bv = *(const float4*)&bias[col];
#pragma unroll
      for (int mi = 0; mi < FM; mi++) {
        const int row = rowG0 + mi * 16 + l16;
        float v0 = acc[mi][ni][0] + bv.x;
        float v1 = acc[mi][ni][1] + bv.y;
        float v2 = acc[mi][ni][2] + bv.z;
        float v3 = acc[mi][ni][3] + bv.w;
        if (RELU) {
          v0 = fmaxf(v0, 0.f); v1 = fmaxf(v1, 0.f);
          v2 = fmaxf(v2, 0.f); v3 = fmaxf(v3, 0.f);
        }
        f32x4 o = {v0, v1, v2, v3};
        *(f32x4*)&Cf[(size_t)row * N + col] = o;
      }
    }
  } else {
    // LDS-staged coalesced epilogue (BN=256 only; 256 rows x 512 B = 128 KB
    // fits the 131072-B K-loop LDS exactly).
    __syncthreads();   // all waves done reading K-loop chunks
    {
      char* cb = (char*)lds;
      const int rowL0 = wm * 128;
      const int colL0 = wn * 64;
      const bool store_bf16 = (bn * BN >= bf16_from_col);
#pragma unroll
      for (int mi = 0; mi < FM; mi++) {
        const int row = rowL0 + mi * 16 + l16;
        const int sw  = row & 7;
#pragma unroll
        for (int ni = 0; ni < 4; ni++) {
          const int col = colL0 + ni * 16 + quad * 4;   // local col of reg 0
          float4 bv = {0.f, 0.f, 0.f, 0.f};
          if (bias != nullptr) bv = *(const float4*)&bias[bn * BN + col];
          float v0 = acc[mi][ni][0] + bv.x;
          float v1 = acc[mi][ni][1] + bv.y;
          float v2 = acc[mi][ni][2] + bv.z;
          float v3 = acc[mi][ni][3] + bv.w;
          if (RELU) {
            v0 = fmaxf(v0, 0.f); v1 = fmaxf(v1, 0.f);
            v2 = fmaxf(v2, 0.f); v3 = fmaxf(v3, 0.f);
          }
          const int ch = (col >> 3) ^ sw;               // 16-B chunk swizzle
          char* p = cb + row * 512 + (ch << 4) + ((quad & 1) << 3);
          if (store_bf16) {
            bf16x4 o = {(bf16)v0, (bf16)v1, (bf16)v2, (bf16)v3};
            *(bf16x4*)p = o;
          } else {
            f16x4 o = {(f16)v0, (f16)v1, (f16)v2, (f16)v3};
            *(f16x4*)p = o;
          }
        }
      }
    }
    __syncthreads();
    {
      const char* cb = (const char*)lds;
      const int rr0 = tid >> 5;          // 0..15
      const int cc  = tid & 31;          // 16-B chunk within the 512-B row
      const size_t rowBytes = (size_t)N * 2;
      char* gbase = (char*)Cp + (size_t)(bm * 256) * rowBytes
                  + (size_t)bn * BN * 2 + (size_t)cc * 16;
#pragma unroll
      for (int it = 0; it < 16; it++) {
        const int row = it * 16 + rr0;
        const int ch  = cc ^ (row & 7);
        u32x4v v = *(const u32x4v*)(cb + row * 512 + (ch << 4));
        *(u32x4v*)(gbase + (size_t)row * rowBytes) = v;
      }
    }
  }
  (void)M;
}

// ---------------------------------------------------------------------------
// Fused flash attention v4 (32x32x16 MFMA) -- unchanged (round-1 passing).
// ---------------------------------------------------------------------------
__global__ __launch_bounds__(256, 4)
void attn_kernel(const f16* __restrict__ qkv, f16* __restrict__ ctx,
                 float scale2, float c2) {
  __shared__ __align__(16) char pool[33280];
  f16*  Ks = (f16*)pool;              // [key 0..127] x 64 f16, XOR-octet swizzle; Q preload overlays
  bf16* Vt = (bf16*)(pool + 16384);   // [d 0..63] stride 132 bf16

  const int tid  = threadIdx.x;
  const int wave = tid >> 6;
  const int lane = tid & 63;
  const int l31  = lane & 31;
  const int hi   = lane >> 5;

  const int flat = blockIdx.x;
  const int bh   = flat & 127;
  const int qt   = flat >> 7;
  const int b    = bh >> 4;
  const int h    = bh & 15;

  const int rs = 3 * E_SZ;
  const size_t tokbase = (size_t)b * S_SZ;

  const int su  = lane >> 3;
  const int soc = (lane & 7) ^ su;

  {
    const f16* gq = qkv + (tokbase + qt * 128 + wave * 8 + su) * (size_t)rs + h * HD_SZ + soc * 8;
#pragma unroll
    for (int i = 0; i < 4; i++)
      async_ld16(gq + (size_t)i * 32 * rs, pool + (i * 32 + wave * 8) * 128);
  }
  __syncthreads();

  f16x8 aq[4];
  {
    const int qrow = wave * 32 + l31;
#pragma unroll
    for (int ks = 0; ks < 4; ks++)
      aq[ks] = *(const f16x8*)&Ks[qrow * 64 + (((ks * 2 + hi) ^ (qrow & 7)) << 3)];
  }

  float Lp = 0.f;
  f32x16 oacc[2];
#pragma unroll
  for (int nb = 0; nb < 2; nb++)
#pragma unroll
    for (int i = 0; i < 16; i++) oacc[nb][i] = 0.f;

  const int vc  = (tid & 7) * 8;
  const int vk0 = (tid >> 3) * 4;

  for (int t = 0; t < S_SZ / 128; t++) {
    __syncthreads();
    {
      const f16* gk = qkv + (tokbase + t * 128 + wave * 8 + su) * (size_t)rs + E_SZ + h * HD_SZ + soc * 8;
#pragma unroll
      for (int i = 0; i < 4; i++)
        async_ld16(gk + (size_t)i * 32 * rs, pool + (i * 32 + wave * 8) * 128);
    }
    {
      const bf16* gv = (const bf16*)qkv + (tokbase + t * 128 + vk0) * (size_t)rs + 2 * E_SZ + h * HD_SZ + vc;
      bf16x8 v0 = *(const bf16x8*)(gv);
      bf16x8 v1 = *(const bf16x8*)(gv + rs);
      bf16x8 v2 = *(const bf16x8*)(gv + 2 * rs);
      bf16x8 v3 = *(const bf16x8*)(gv + 3 * rs);
#pragma unroll
      for (int e = 0; e < 8; e++) {
        bf16x4 pk = {v0[e], v1[e], v2[e], v3[e]};
        *(bf16x4*)&Vt[(vc + e) * 132 + vk0] = pk;
      }
    }
    __syncthreads();

#pragma unroll
    for (int nt = 0; nt < 4; nt++) {
      f32x16 sacc;
#pragma unroll
      for (int i = 0; i < 16; i++) sacc[i] = 0.f;

      const int krow = nt * 32 + l31;
      __builtin_amdgcn_s_setprio(1);
#pragma unroll
      for (int ks = 0; ks < 4; ks++) {
        f16x8 kf = *(const f16x8*)&Ks[krow * 64 + (((ks * 2 + hi) ^ (krow & 7)) << 3)];
        sacc = __builtin_amdgcn_mfma_f32_32x32x16_f16(kf, aq[ks], sacc, 0, 0, 0);
      }
      __builtin_amdgcn_s_setprio(0);

      uint32_t w[8];
#pragma unroll
      for (int j = 0; j < 8; j++) {
        float p0 = exp2f(fmaf(sacc[2 * j],     scale2, -c2));
        float p1 = exp2f(fmaf(sacc[2 * j + 1], scale2, -c2));
        Lp += p0 + p1;
        bf16x2 pk2 = {(bf16)p0, (bf16)p1};
        w[j] = __builtin_bit_cast(uint32_t, pk2);
      }
      permswap(w[0], w[2]);
      permswap(w[1], w[3]);
      permswap(w[4], w[6]);
      permswap(w[5], w[7]);
      u32x4v pe = {w[0], w[1], w[2], w[3]};
      u32x4v po = {w[4], w[5], w[6], w[7]};
      bf16x8 pa[2] = {__builtin_bit_cast(bf16x8, pe), __builtin_bit_cast(bf16x8, po)};

      __builtin_amdgcn_s_setprio(1);
#pragma unroll
      for (int nb = 0; nb < 2; nb++) {
        const int d = nb * 32 + l31;
#pragma unroll
        for (int kst = 0; kst < 2; kst++) {
          const int key = (nt * 2 + kst) * 16 + hi * 8;
          bf16x4 blo = *(const bf16x4*)&Vt[d * 132 + key];
          bf16x4 bhi = *(const bf16x4*)&Vt[d * 132 + key + 4];
          bf16x8 bv = __builtin_shufflevector(blo, bhi, 0, 1, 2, 3, 4, 5, 6, 7);
          oacc[nb] = __builtin_amdgcn_mfma_f32_32x32x16_bf16(pa[kst], bv, oacc[nb], 0, 0, 0);
        }
      }
      __builtin_amdgcn_s_setprio(0);
    }
  }

  float Lfull = Lp + __shfl_xor(Lp, 32, 64);
  const float inv = 1.f / Lfull;
#pragma unroll
  for (int r = 0; r < 16; r++) {
    const int qrow = (r & 3) + 8 * (r >> 2) + 4 * hi;
    const float invr = __shfl(inv, qrow, 32);
    const size_t row = tokbase + (size_t)qt * 128 + wave * 32 + qrow;
#pragma unroll
    for (int nb = 0; nb < 2; nb++)
      ctx[row * (size_t)E_SZ + h * HD_SZ + nb * 32 + l31] = (f16)(oacc[nb][r] * invr);
  }
}

// ---------------------------------------------------------------------------
// LayerNorm(a + res) * g + b  over rows of 1024, fp32 (+optional f16 copy).
// ---------------------------------------------------------------------------
__global__ void ln_kernel(const float* __restrict__ a, const float* __restrict__ res,
                          const float* __restrict__ g, const float* __restrict__ bta,
                          float* __restrict__ out32, f16* __restrict__ out16) {
  const int row  = blockIdx.x;
  const int tid  = threadIdx.x;
  const int wave = tid >> 6;
  const int lane = tid & 63;
  const size_t base = (size_t)row * 1024;
  const int c = tid * 4;

  float4 va = *(const float4*)&a[base + c];
  float4 vr = *(const float4*)&res[base + c];
  float v0 = va.x + vr.x, v1 = va.y + vr.y, v2 = va.z + vr.z, v3 = va.w + vr.w;

  __shared__ float r1[4], r2[4];
  float s = v0 + v1 + v2 + v3;
#pragma unroll
  for (int off = 32; off; off >>= 1) s += __shfl_xor(s, off, 64);
  if (lane == 0) r1[wave] = s;
  __syncthreads();
  const float mu = (r1[0] + r1[1] + r1[2] + r1[3]) * (1.f / 1024.f);

  float d0 = v0 - mu, d1 = v1 - mu, d2 = v2 - mu, d3 = v3 - mu;
  float ss = d0 * d0 + d1 * d1 + d2 * d2 + d3 * d3;
#pragma unroll
  for (int off = 32; off; off >>= 1) ss += __shfl_xor(ss, off, 64);
  if (lane == 0) r2[wave] = ss;
  __syncthreads();
  const float var = (r2[0] + r2[1] + r2[2] + r2[3]) * (1.f / 1024.f);
  const float rsq = rsqrtf(var + 1e-5f);

  float4 gg = *(const float4*)&g[c];
  float4 bb = *(const float4*)&bta[c];
  float o0 = d0 * rsq * gg.x + bb.x;
  float o1 = d1 * rsq * gg.y + bb.y;
  float o2 = d2 * rsq * gg.z + bb.z;
  float o3 = d3 * rsq * gg.w + bb.w;
  float4 o = {o0, o1, o2, o3};
  *(float4*)&out32[base + c] = o;
  if (out16 != nullptr) {
    f16x4 ob = {(f16)o0, (f16)o1, (f16)o2, (f16)o3};
    *(f16x4*)&out16[base + c] = ob;
  }
}

// ---------------------------------------------------------------------------
// Launch
// ---------------------------------------------------------------------------
extern "C" void kernel_launch(void* const* d_in, const int* in_sizes, int n_in,
                              void* d_out, int out_size, void* d_ws, size_t ws_size,
                              hipStream_t stream) {
  const float* x    = (const float*)d_in[0];
  const float* wqkv = (const float*)d_in[1];
  const float* wo   = (const float*)d_in[2];
  const float* ln1g = (const float*)d_in[3];
  const float* ln1b = (const float*)d_in[4];
  const float* ln2g = (const float*)d_in[5];
  const float* ln2b = (const float*)d_in[6];
  const float* w1   = (const float*)d_in[7];
  const float* b1   = (const float*)d_in[8];
  const float* w2   = (const float*)d_in[9];
  const float* b2   = (const float*)d_in[10];
  float* out = (float*)d_out;

  char* ws = (char*)d_ws;
  f16* w_inb  = (f16*)(ws + 0);
  f16* w_outb = (f16*)(ws + 6291456);
  f16* w1b    = (f16*)(ws + 8388608);
  f16* w2b    = (f16*)(ws + 16777216);
  f16* xb     = (f16*)(ws + 25165824);
  f16* qkv    = (f16*)(ws + 41943040);   // q,k fp16 | v-third bf16
  f16* ctx    = (f16*)(ws + 92274688);
  f16* ff1    = (f16*)(ws + 41943040);
  float* tmp  = (float*)(ws + 109051904);
  float* hbuf = (float*)(ws + 142606336);
  f16* hb     = xb;

  const int NOBF = 1 << 30;

  // one fused cast launch for all 5 fp32->f16 conversions
  cast_all_kernel<<<20480, 256, 0, stream>>>(wqkv, wo, w1, w2, x,
                                             w_inb, w_outb, w1b, w2b, xb);

  // qkv = x @ in_proj_w^T; V-third (cols >= 2048) stored bf16
  gemm256<256, true, false><<<(3 * E_SZ / 256) * (MTOK / 256), 512, 0, stream>>>(
      xb, w_inb, nullptr, qkv, MTOK, 3 * E_SZ, E_SZ, 2048);

  // p = 2^(2.5*dot - 60): 0.25*ln(1024)*log2(e) == 2.5 exactly
  attn_kernel<<<1024, 256, 0, stream>>>(qkv, ctx, 2.5f, 60.0f);

  gemm256<128, false, false><<<(E_SZ / 128) * (MTOK / 256), 512, 0, stream>>>(
      ctx, w_outb, nullptr, tmp, MTOK, E_SZ, E_SZ, NOBF);

  ln_kernel<<<MTOK, 256, 0, stream>>>(tmp, x, ln1g, ln1b, hbuf, hb);

  gemm256<256, true, true><<<(FF_SZ / 256) * (MTOK / 256), 512, 0, stream>>>(
      hb, w1b, b1, ff1, MTOK, FF_SZ, E_SZ, NOBF);

  gemm256<128, false, false><<<(E_SZ / 128) * (MTOK / 256), 512, 0, stream>>>(
      ff1, w2b, b2, tmp, MTOK, E_SZ, FF_SZ, NOBF);

  ln_kernel<<<MTOK, 256, 0, stream>>>(tmp, hbuf, ln2g, ln2b, out, nullptr);

  (void)in_sizes; (void)n_in; (void)out_size; (void)ws_size;
}